// Round 1
// baseline (260.602 us; speedup 1.0000x reference)
//
#include <hip/hip_runtime.h>
#include <cstdint>

// B=4, S=2048, D=1024.  M_qkv = B*S = 8192.
// ws layout (bytes):
//   x_bf  @ 0        : 16,777,216  bf16 [8192][1024] (dead after Vt-proj;
//                      gsum f32[8192][16] overlays @0, written by score)
//   w_bf  @ 16777216 :  6,291,456  bf16 Wq,Wk,Wv each [1024][1024]
//   Qf8   @ 23068672 :  8,388,608  fp8 e4m3 [8192][1024]
//   Kf8   @ 31457280 :  8,388,608  fp8 e4m3 [8192][1024]
//   Vt    @ 39845888 : 16,777,216  bf16 [1024][8192], col = b*2048+s
//   P~    @ 56623104 : 33,554,432  bf16 [4][2048][2048] = exp(s/32), unnorm.

typedef __bf16 bf16x8_t __attribute__((ext_vector_type(8)));
typedef float  f32x4_t  __attribute__((ext_vector_type(4)));
typedef int    i32x8_t  __attribute__((ext_vector_type(8)));
typedef int    i32x4_t  __attribute__((ext_vector_type(4)));

__device__ __forceinline__ uint16_t f2bf(float f) {
    union { float f; uint32_t u; } v; v.f = f;
    return (uint16_t)((v.u + 0x7fffu + ((v.u >> 16) & 1u)) >> 16);  // RNE
}

// fp32 -> OCP e4m3fn, RNE.  Values here are |f| <~ 8, well inside range.
__device__ __forceinline__ uint8_t f2fp8(float f) {
    union { float f; uint32_t u; } v; v.f = f;
    const uint32_t sgn = (v.u >> 31) << 7;
    const uint32_t mag = v.u & 0x7fffffffu;
    uint32_t out;
    if (mag < 0x3c800000u) {                       // |f| < 2^-6: subnormal
        out = (uint32_t)__builtin_rintf(__builtin_fabsf(f) * 512.0f); // 0..8
    } else {
        uint32_t t = mag + 0x7ffffu + ((mag >> 20) & 1u);  // RNE at bit 20
        out = (t >> 20) - 960u;                            // (E<<3|m) - (120<<3)
        if (out > 0x7eu) out = 0x7eu;                      // clamp to 448
    }
    return (uint8_t)(sgn | out);
}

__device__ __forceinline__ void gload_lds16(const void* g, void* lds) {
    __builtin_amdgcn_global_load_lds(
        (const __attribute__((address_space(1))) void*)g,
        (__attribute__((address_space(3))) void*)lds, 16, 0, 0);
}

// Raw barriers: no compiler-inserted vmcnt(0) drain (that drain is the m97
// ~900TF ceiling).  "memory" clobber = compiler-level fence so LDS reads /
// LDS-DMA issues cannot migrate across phases.
#define BAR()   asm volatile("s_barrier" ::: "memory")
#define WLGKM() asm volatile("s_waitcnt lgkmcnt(0)" ::: "memory")

// ---------------------------------------------------------------------------
// 8-phase 256xBN bf16 B^T GEMM (T2+T3+T4+T5), BK=64, 512 thr = 2x4 waves.
//
// LDS per matrix: [2 slot][2 kh][rows][32 k], granule = one (matrix, kh) =
// rows*32 bf16.  Chunk swizzle: 16B chunk p of row r holds global chunk
// p ^ ((r>>2)&3)  -> ds_read_b128 is <=2-way (free) and the granule is a
// contiguous gload_lds16 span.
//
// Window t (4 phases) computes K-tile t from slot t&1.  Phase = (qm, kh):
//   p1 (qm0,kh0)+B-kh0 read | stage A-kh1(t+1) -> other slot
//   p2 (qm1,kh0)           | stage B-kh0(t+2) -> this slot   (read done p1)
//   p3 (qm0,kh1)+B-kh1 read| stage A-kh0(t+2) -> this slot   (read done p2)
//   p4 (qm1,kh1)           | stage B-kh1(t+2) -> this slot   (read done p3)
//                          | vmcnt(2+2*LB)  -> all but 3 newest granules
//                            landed => next window's K-tile is resident.
// Each granule is staged in the phase AFTER its previous contents' last
// read (barrier-separated => WAR-safe); consumers read granules >=4 stages
// old (vmcnt-safe).  B-frags are register-held across phase pairs, which is
// why overwriting B-kh0 during p2 is legal.
//
// EPI: 1 = +bias[n], fp8 out (Q/K)   2 = +bias[m], bf16 out (Vt)
//      4 = acc * 1/sum16(gsum_row), fp32 out (PV)
// ---------------------------------------------------------------------------
template <int BN, int EPI, typename OutT>
__global__ __launch_bounds__(512, 2) void gemm8p(
    const uint16_t* __restrict__ A, int lda, long long sAz,
    const uint16_t* __restrict__ B, int ldb, long long sBz,
    OutT* __restrict__ C, int ldc, long long sCz,
    const float* __restrict__ bias0, const float* __restrict__ bias1,
    const float* __restrict__ gsum, int K)
{
    constexpr int NF    = BN / 64;    // n-frags per wave (4 or 2)
    constexpr int LB    = BN / 128;   // gloads per B granule per thread (2 or 1)
    constexpr int BSLOT = BN * 128;   // bytes per B LDS slot
    constexpr int BKH   = BN * 64;    // bytes per B kh-granule

    __shared__ uint16_t ldsA[32768];        // 64 KiB: [2][2][256][32]
    __shared__ uint16_t ldsB[BN * 128];     // [2][2][BN][32]
    __shared__ float    inv_denom[256];

    const int tid  = threadIdx.x;
    const int wv   = tid >> 6;
    const int lane = tid & 63;
    const int quad = lane >> 4;
    const int l15  = lane & 15;
    const int wm   = wv >> 2;   // 0..1  (wave row-block)
    const int wn   = wv & 3;    // 0..3  (wave col-block)
    const int z    = blockIdx.z;

    A += (long long)z * sAz;
    B += (long long)z * sBz;
    C += (long long)z * sCz;

    const int m0 = blockIdx.x * 256;
    const int n0 = blockIdx.y * BN;

    if (EPI == 4) {
        if (tid < 256) {
            const float* gp = gsum + (long long)z * 32768 + (m0 + tid) * 16;
            float s = 0.f;
#pragma unroll
            for (int t = 0; t < 16; ++t) s += gp[t];
            inv_denom[tid] = 1.f / s;
        }
        // visibility via prologue barrier
    }

    // ---- staging geometry: thread covers 16B slot tid (rows 0..127) and,
    // for 256-row granules, slot tid+512 (rows 128..255, same k-chunk).
    const int r  = tid >> 2;                          // 0..127
    const int ca = (tid & 3) ^ ((tid >> 4) & 3);      // global k-chunk held
    const uint16_t* aS = A + (long long)(m0 + r) * lda + ca * 8;
    const uint16_t* bS = B + (long long)(n0 + r) * ldb + ca * 8;
    const int dOf = wv * 1024;   // wave-uniform LDS dest (HW adds lane*16)

    auto STAGE_A = [&](int kt, int h, int sl) {
        const uint16_t* s = aS + kt * 64 + h * 32;
        char* d = (char*)ldsA + sl * 32768 + h * 16384 + dOf;
        gload_lds16(s, d);
        gload_lds16(s + (long long)128 * lda, d + 8192);
    };
    auto STAGE_B = [&](int kt, int h, int sl) {
        const uint16_t* s = bS + kt * 64 + h * 32;
        char* d = (char*)ldsB + sl * BSLOT + h * BKH + dOf;
        gload_lds16(s, d);
        if (LB == 2) gload_lds16(s + (long long)128 * ldb, d + 8192);
    };

    // ---- frag-read geometry (chunk swizzle index = quad ^ (l15>>2))
    const int csw  = ((quad ^ (l15 >> 2)) & 3) * 16;
    const int aOff = (wm * 128 + l15) * 64 + csw;
    const int bOff = (wn * (BN / 4) + l15) * 64 + csw;

    f32x4_t acc[8][NF];
#pragma unroll
    for (int i = 0; i < 8; ++i)
#pragma unroll
        for (int j = 0; j < NF; ++j) acc[i][j] = f32x4_t{0.f, 0.f, 0.f, 0.f};

    const int NT = K >> 6;

    // ---- prologue: tile0 complete + tile1 {B-kh0, A-kh0, B-kh1}
    STAGE_B(0, 0, 0); STAGE_A(0, 0, 0); STAGE_B(0, 1, 0); STAGE_A(0, 1, 0);
    STAGE_B(1, 0, 1); STAGE_A(1, 0, 1); STAGE_B(1, 1, 1);
    if constexpr (LB == 2) asm volatile("s_waitcnt vmcnt(6)" ::: "memory");
    else                   asm volatile("s_waitcnt vmcnt(4)" ::: "memory");
    BAR();

    for (int t = 0; t < NT; ++t) {
        const int sl = t & 1;
        const int so = sl ^ 1;
        const int t1 = (t + 1 < NT) ? t + 1 : 0;   // wrap: keeps vmcnt counts
        const int t2 = (t + 2 < NT) ? t + 2 : 0;   // uniform; wraps never read
        const char* Ab = (const char*)ldsA + sl * 32768;
        const char* Bb = (const char*)ldsB + sl * BSLOT;

        bf16x8_t af[4], bfv[NF];

        // -- phase 1: (qm0, kh0) + read B-kh0; stage A-kh1(t+1) -> other slot
#pragma unroll
        for (int i = 0; i < 4; ++i)
            af[i] = *(const bf16x8_t*)(Ab + i * 1024 + aOff);
#pragma unroll
        for (int j = 0; j < NF; ++j)
            bfv[j] = *(const bf16x8_t*)(Bb + j * 1024 + bOff);
        STAGE_A(t1, 1, so);
        BAR(); WLGKM();
        __builtin_amdgcn_s_setprio(1);
#pragma unroll
        for (int i = 0; i < 4; ++i)
#pragma unroll
            for (int j = 0; j < NF; ++j)
                acc[i][j] = __builtin_amdgcn_mfma_f32_16x16x32_bf16(
                    af[i], bfv[j], acc[i][j], 0, 0, 0);
        __builtin_amdgcn_s_setprio(0);
        BAR();

        // -- phase 2: (qm1, kh0); stage B-kh0(t+2) -> this slot
#pragma unroll
        for (int i = 0; i < 4; ++i)
            af[i] = *(const bf16x8_t*)(Ab + 4096 + i * 1024 + aOff);
        STAGE_B(t2, 0, sl);
        BAR(); WLGKM();
        __builtin_amdgcn_s_setprio(1);
#pragma unroll
        for (int i = 0; i < 4; ++i)
#pragma unroll
            for (int j = 0; j < NF; ++j)
                acc[4 + i][j] = __builtin_amdgcn_mfma_f32_16x16x32_bf16(
                    af[i], bfv[j], acc[4 + i][j], 0, 0, 0);
        __builtin_amdgcn_s_setprio(0);
        BAR();

        // -- phase 3: (qm0, kh1) + read B-kh1; stage A-kh0(t+2) -> this slot
#pragma unroll
        for (int i = 0; i < 4; ++i)
            af[i] = *(const bf16x8_t*)(Ab + 16384 + i * 1024 + aOff);
#pragma unroll
        for (int j = 0; j < NF; ++j)
            bfv[j] = *(const bf16x8_t*)(Bb + BKH + j * 1024 + bOff);
        STAGE_A(t2, 0, sl);
        BAR(); WLGKM();
        __builtin_amdgcn_s_setprio(1);
#pragma unroll
        for (int i = 0; i < 4; ++i)
#pragma unroll
            for (int j = 0; j < NF; ++j)
                acc[i][j] = __builtin_amdgcn_mfma_f32_16x16x32_bf16(
                    af[i], bfv[j], acc[i][j], 0, 0, 0);
        __builtin_amdgcn_s_setprio(0);
        BAR();

        // -- phase 4: (qm1, kh1); stage B-kh1(t+2) -> this slot; counted vmcnt
#pragma unroll
        for (int i = 0; i < 4; ++i)
            af[i] = *(const bf16x8_t*)(Ab + 16384 + 4096 + i * 1024 + aOff);
        STAGE_B(t2, 1, sl);
        BAR(); WLGKM();
        __builtin_amdgcn_s_setprio(1);
#pragma unroll
        for (int i = 0; i < 4; ++i)
#pragma unroll
            for (int j = 0; j < NF; ++j)
                acc[4 + i][j] = __builtin_amdgcn_mfma_f32_16x16x32_bf16(
                    af[i], bfv[j], acc[4 + i][j], 0, 0, 0);
        __builtin_amdgcn_s_setprio(0);
        if constexpr (LB == 2) asm volatile("s_waitcnt vmcnt(6)" ::: "memory");
        else                   asm volatile("s_waitcnt vmcnt(4)" ::: "memory");
        BAR();
    }

    // ---- epilogue (C/D layout: col = lane&15, row = quad*4 + reg)
    if (EPI == 1 || EPI == 2) {
        const float* bias = (z == 0) ? bias0 : bias1;
#pragma unroll
        for (int fi = 0; fi < 8; ++fi) {
            const int mb = m0 + wm * 128 + fi * 16 + quad * 4;
            float rb[4];
            if (EPI == 2) {
#pragma unroll
                for (int rr = 0; rr < 4; ++rr) rb[rr] = bias[mb + rr];
            }
#pragma unroll
            for (int fj = 0; fj < NF; ++fj) {
                const int n = n0 + wn * (BN / 4) + fj * 16 + l15;
                const float cb = (EPI == 1) ? bias[n] : 0.f;
#pragma unroll
                for (int rr = 0; rr < 4; ++rr) {
                    const float vv = acc[fi][fj][rr] + ((EPI == 1) ? cb : rb[rr]);
                    if (sizeof(OutT) == 1)
                        ((uint8_t*)C)[(long long)(mb + rr) * ldc + n] = f2fp8(vv);
                    else
                        ((uint16_t*)C)[(long long)(mb + rr) * ldc + n] = f2bf(vv);
                }
            }
        }
    } else {  // EPI == 4
#pragma unroll
        for (int fi = 0; fi < 8; ++fi) {
            const int rl = wm * 128 + fi * 16 + quad * 4;
            const int mb = m0 + rl;
#pragma unroll
            for (int fj = 0; fj < NF; ++fj) {
                const int n = n0 + wn * (BN / 4) + fj * 16 + l15;
#pragma unroll
                for (int rr = 0; rr < 4; ++rr)
                    ((float*)C)[(long long)(mb + rr) * ldc + n] =
                        acc[fi][fj][rr] * inv_denom[rl + rr];
            }
        }
    }
}

// ---------------------------------------------------------------------------
// fp8 score GEMM: P~ = exp((Q K^T)/32), MX-fp8 MFMA K=128 with unit scales.
// (unchanged, r5-verified)
// ---------------------------------------------------------------------------
__global__ __launch_bounds__(256, 3) void score_f8(
    const uint8_t* __restrict__ Qf8, const uint8_t* __restrict__ Kf8,
    uint16_t* __restrict__ P, float* __restrict__ gsum, float alpha)
{
    __shared__ uint8_t ldsA[128 * 128];
    __shared__ uint8_t ldsB[128 * 128];

    const int tid  = threadIdx.x;
    const int wave = tid >> 6;
    const int lane = tid & 63;
    const int quad = lane >> 4;
    const int l15  = lane & 15;
    const int z    = blockIdx.z;

    const uint8_t* A = Qf8 + (long long)z * 2097152;
    const uint8_t* B = Kf8 + (long long)z * 2097152;
    uint16_t* C = P + (long long)z * 4194304;

    const int m0 = blockIdx.x * 128;
    const int n0 = blockIdx.y * 128;

    const uint8_t* gA[4];
    const uint8_t* gB[4];
    uint8_t* lA[4];
    uint8_t* lB[4];
#pragma unroll
    for (int c = 0; c < 4; ++c) {
        const int s   = (c * 4 + wave) * 64 + lane;
        const int r   = s >> 3;
        const int col = ((s & 7) ^ (r & 7)) * 16;
        gA[c] = A + (long long)(m0 + r) * 1024 + col;
        gB[c] = B + (long long)(n0 + r) * 1024 + col;
        lA[c] = ldsA + (c * 4 + wave) * 1024;
        lB[c] = ldsB + (c * 4 + wave) * 1024;
    }

    const int m_off = (wave & 1) * 64;
    const int n_off = (wave >> 1) * 64;

    f32x4_t acc[4][4];
#pragma unroll
    for (int i = 0; i < 4; ++i)
#pragma unroll
        for (int j = 0; j < 4; ++j)
            acc[i][j] = f32x4_t{0.f, 0.f, 0.f, 0.f};

    const int h0 = quad * 2;
    const int h1 = quad * 2 + 1;

    for (int k0 = 0; k0 < 1024; k0 += 128) {
#pragma unroll
        for (int c = 0; c < 4; ++c) gload_lds16(gA[c], lA[c]);
#pragma unroll
        for (int c = 0; c < 4; ++c) gload_lds16(gB[c], lB[c]);
#pragma unroll
        for (int c = 0; c < 4; ++c) { gA[c] += 128; gB[c] += 128; }
        __syncthreads();

        i32x8_t af[4], bfr[4];
#pragma unroll
        for (int i = 0; i < 4; ++i) {
            const int m = m_off + i * 16 + l15;
            const int sw = m & 7;
            const i32x4_t lo = *(const i32x4_t*)(ldsA + m * 128 + (h0 ^ sw) * 16);
            const i32x4_t hi = *(const i32x4_t*)(ldsA + m * 128 + (h1 ^ sw) * 16);
            af[i] = i32x8_t{lo[0], lo[1], lo[2], lo[3], hi[0], hi[1], hi[2], hi[3]};
        }
#pragma unroll
        for (int j = 0; j < 4; ++j) {
            const int n = n_off + j * 16 + l15;
            const int sw = n & 7;
            const i32x4_t lo = *(const i32x4_t*)(ldsB + n * 128 + (h0 ^ sw) * 16);
            const i32x4_t hi = *(const i32x4_t*)(ldsB + n * 128 + (h1 ^ sw) * 16);
            bfr[j] = i32x8_t{lo[0], lo[1], lo[2], lo[3], hi[0], hi[1], hi[2], hi[3]};
        }
#pragma unroll
        for (int i = 0; i < 4; ++i)
#pragma unroll
            for (int j = 0; j < 4; ++j)
                acc[i][j] = __builtin_amdgcn_mfma_scale_f32_16x16x128_f8f6f4(
                    af[i], bfr[j], acc[i][j],
                    0, 0,
                    0, 0x7f7f7f7f,
                    0, 0x7f7f7f7f);
        __syncthreads();
    }

    float rs[4][4];
#pragma unroll
    for (int i = 0; i < 4; ++i)
#pragma unroll
        for (int r = 0; r < 4; ++r) rs[i][r] = 0.f;
#pragma unroll
    for (int i = 0; i < 4; ++i) {
        const int mb = m0 + m_off + i * 16 + quad * 4;
#pragma unroll
        for (int j = 0; j < 4; ++j) {
            const int n = n0 + n_off + j * 16 + l15;
#pragma unroll
            for (int r = 0; r < 4; ++r) {
                const float e = exp2f(acc[i][j][r] * alpha);
                rs[i][r] += e;
                C[(long long)(mb + r) * 2048 + n] = f2bf(e);
            }
        }
    }
#pragma unroll
    for (int m = 1; m < 16; m <<= 1)
#pragma unroll
        for (int i = 0; i < 4; ++i)
#pragma unroll
            for (int r = 0; r < 4; ++r)
                rs[i][r] += __shfl_xor(rs[i][r], m);
    float* lp = (float*)ldsA;
    if (l15 == 0) {
#pragma unroll
        for (int i = 0; i < 4; ++i)
#pragma unroll
            for (int r = 0; r < 4; ++r)
                lp[wave * 64 + i * 16 + quad * 4 + r] = rs[i][r];
    }
    __syncthreads();
    if (tid < 128) {
        const float s = lp[(tid >> 6) * 64 + (tid & 63)] +
                        lp[((tid >> 6) + 2) * 64 + (tid & 63)];
        gsum[(long long)z * 32768 + (m0 + tid) * 16 + blockIdx.y] = s;
    }
}

// fp32 -> bf16 for x (blocks 0..8191) and Wq/Wk/Wv (blocks 8192..11263).
__global__ void cvt_all(const float* __restrict__ x,
                        const float* __restrict__ Wq, const float* __restrict__ Wk,
                        const float* __restrict__ Wv,
                        uint16_t* __restrict__ x_bf, uint16_t* __restrict__ w_bf) {
    const int b = blockIdx.x;
    const float* src;
    uint16_t* dst;
    int i;
    if (b < 8192) {
        src = x; dst = x_bf; i = b * 256 + threadIdx.x;
    } else {
        const int wz = (b - 8192) >> 10;
        const int rb = (b - 8192) & 1023;
        src = (wz == 0) ? Wq : (wz == 1) ? Wk : Wv;
        dst = w_bf + (long long)wz * 1048576;
        i = rb * 256 + threadIdx.x;
    }
    const float4 f = ((const float4*)src)[i];
    ushort4 o;
    o.x = f2bf(f.x); o.y = f2bf(f.y); o.z = f2bf(f.z); o.w = f2bf(f.w);
    ((ushort4*)dst)[i] = o;
}

extern "C" void kernel_launch(void* const* d_in, const int* in_sizes, int n_in,
                              void* d_out, int out_size, void* d_ws, size_t ws_size,
                              hipStream_t stream) {
    const float* x  = (const float*)d_in[0];
    const float* Wq = (const float*)d_in[1];
    const float* bq = (const float*)d_in[2];
    const float* Wk = (const float*)d_in[3];
    const float* bk = (const float*)d_in[4];
    const float* Wv = (const float*)d_in[5];
    const float* bv = (const float*)d_in[6];
    float* out = (float*)d_out;

    char* w = (char*)d_ws;
    uint16_t* x_bf = (uint16_t*)(w);
    float*    gsum = (float*)(w);                 // overlays dead x_bf
    uint16_t* w_bf = (uint16_t*)(w + 16777216);
    uint8_t*  Qf8  = (uint8_t*)(w + 23068672);
    uint8_t*  Kf8  = (uint8_t*)(w + 31457280);
    uint16_t* Vt   = (uint16_t*)(w + 39845888);
    uint16_t* Pb   = (uint16_t*)(w + 56623104);

    // 1) fp32 -> bf16 conversions (x + all three W)
    cvt_all<<<11264, 256, 0, stream>>>(x, Wq, Wk, Wv, x_bf, w_bf);

    // 2) Q,K = x @ W^T + b  [8192,1024] fp8 out.  256x256 tiles: (32,4,2)=256 wg
    gemm8p<256, 1, uint8_t><<<dim3(32, 4, 2), 512, 0, stream>>>(
        x_bf, 1024, 0LL,
        w_bf, 1024, 1048576LL,
        Qf8, 1024, 8388608LL,
        bq, bk, nullptr, 1024);

    // 2b) Vt[e, b*2048+s] = Wv x^T + bv  [1024,8192].  256x128: (4,64,1)=256 wg
    gemm8p<128, 2, uint16_t><<<dim3(4, 64, 1), 512, 0, stream>>>(
        w_bf + 2097152, 1024, 0LL,
        x_bf, 1024, 0LL,
        Vt, 8192, 0LL,
        bv, bv, nullptr, 1024);

    // 3) P~_b = exp((Q_b K_b^T)/32) via MX-fp8 K=128; alpha = (1/32)*log2(e)
    score_f8<<<dim3(16, 16, 4), 256, 0, stream>>>(
        Qf8, Kf8, Pb, gsum, 0.045084222f);

    // 4) O_b = (P~_b @ V_b) / denom : fp32 out.  256x128: (8,8,4)=256 wg
    gemm8p<128, 4, float><<<dim3(8, 8, 4), 512, 0, stream>>>(
        Pb, 2048, 4194304LL,
        Vt, 8192, 2048LL,
        out, 1024, 2097152LL,
        nullptr, nullptr, gsum, 2048);
}

// Round 3
// 251.552 us; speedup vs baseline: 1.0360x; 1.0360x over previous
//
#include <hip/hip_runtime.h>
#include <cstdint>

// B=4, S=2048, D=1024.  M_qkv = B*S = 8192.
// ws layout (bytes):
//   x_bf  @ 0        : 16,777,216  bf16 [8192][1024] (dead after Vt-proj;
//                      gsum f32[8192][16] overlays @0, written by score)
//   w_bf  @ 16777216 :  6,291,456  bf16 Wq,Wk,Wv each [1024][1024]
//   Qf8   @ 23068672 :  8,388,608  fp8 e4m3 [8192][1024]
//   Kf8   @ 31457280 :  8,388,608  fp8 e4m3 [8192][1024]
//   Vt    @ 39845888 : 16,777,216  bf16 [1024][8192], col = b*2048+s
//   P~    @ 56623104 : 33,554,432  bf16 [4][2048][2048] = exp(s/32), unnorm.

typedef __bf16 bf16x8_t __attribute__((ext_vector_type(8)));
typedef float  f32x4_t  __attribute__((ext_vector_type(4)));
typedef int    i32x8_t  __attribute__((ext_vector_type(8)));
typedef int    i32x4_t  __attribute__((ext_vector_type(4)));

__device__ __forceinline__ uint16_t f2bf(float f) {
    union { float f; uint32_t u; } v; v.f = f;
    return (uint16_t)((v.u + 0x7fffu + ((v.u >> 16) & 1u)) >> 16);  // RNE
}

// fp32 -> OCP e4m3fn, RNE.  Values here are |f| <~ 8, well inside range.
__device__ __forceinline__ uint8_t f2fp8(float f) {
    union { float f; uint32_t u; } v; v.f = f;
    const uint32_t sgn = (v.u >> 31) << 7;
    const uint32_t mag = v.u & 0x7fffffffu;
    uint32_t out;
    if (mag < 0x3c800000u) {                       // |f| < 2^-6: subnormal
        out = (uint32_t)__builtin_rintf(__builtin_fabsf(f) * 512.0f); // 0..8
    } else {
        uint32_t t = mag + 0x7ffffu + ((mag >> 20) & 1u);  // RNE at bit 20
        out = (t >> 20) - 960u;                            // (E<<3|m) - (120<<3)
        if (out > 0x7eu) out = 0x7eu;                      // clamp to 448
    }
    return (uint8_t)(sgn | out);
}

__device__ __forceinline__ void gload_lds16(const void* g, void* lds) {
    __builtin_amdgcn_global_load_lds(
        (const __attribute__((address_space(1))) void*)g,
        (__attribute__((address_space(3))) void*)lds, 16, 0, 0);
}

// Raw barriers: no compiler-inserted vmcnt(0) drain (that drain is the m97
// ~900TF ceiling).  "memory" clobber = compiler-level fence so LDS reads /
// LDS-DMA issues cannot migrate across phases.
#define BAR()   asm volatile("s_barrier" ::: "memory")
#define WLGKM() asm volatile("s_waitcnt lgkmcnt(0)" ::: "memory")

// ---------------------------------------------------------------------------
// 256xBN bf16 B^T GEMM (T2+T3+T4+T5), BK=64, 512 thr = 2x4 waves.
//
// LDS per matrix: [2 slot][2 kh][rows][32 k], granule = one (matrix, kh).
// Chunk swizzle (R1 post-mortem fix): 16B chunk p of row r holds global
// chunk p ^ ((r>>1)&3).  Any 8 consecutive lanes of a frag ds_read_b128 hit
// bank-groups {(l15&1)*4 + (quad^((l15>>1)&3))} = a permutation of 0..7
// -> conflict-free phases.  ((r>>2)&3 gave 4 groups x 2-way = 5.24M
// conflict cycles in R1.)
//
// NF==4 (BN=256): 4 phases/K-tile, phase=(qm,kh), 16 MFMA each, B-frags
//   register-held across phase pairs, 1 granule (2 loads) staged per phase,
//   vmcnt(6) once per K-tile (3 granules in flight).
// NF==2 (BN=128): 2 phases/K-tile, phase=kh, all 8 m-frags x 2 n-frags =
//   16 MFMA each.  Pair-granule pipeline: phase j reads pair j, stages pair
//   j+3 (pair = {A,B} of one kh = 3 loads); vmcnt(6) per phase keeps pairs
//   j+1, j+2 in flight.  Pair j+3 overwrites (slot,kh) of pair j-1, whose
//   ds_reads drained at phase j-1's lgkmcnt(0) before its end-barrier.
//
// EPI: 1 = +bias[n], fp8 out (Q/K)   2 = +bias[m], bf16 out (Vt)
//      4 = acc * 1/sum16(gsum_row), fp32 out (PV)
// ---------------------------------------------------------------------------
template <int BN, int EPI, typename OutT>
__global__ __launch_bounds__(512, 2) void gemm8p(
    const uint16_t* __restrict__ A, int lda, long long sAz,
    const uint16_t* __restrict__ B, int ldb, long long sBz,
    OutT* __restrict__ C, int ldc, long long sCz,
    const float* __restrict__ bias0, const float* __restrict__ bias1,
    const float* __restrict__ gsum, int K)
{
    constexpr int NF    = BN / 64;    // n-frags per wave (4 or 2)
    constexpr int LB    = BN / 128;   // gloads per B granule per thread (2 or 1)
    constexpr int BSLOT = BN * 128;   // bytes per B LDS slot
    constexpr int BKH   = BN * 64;    // bytes per B kh-granule

    __shared__ uint16_t ldsA[32768];        // 64 KiB: [2][2][256][32]
    __shared__ uint16_t ldsB[BN * 128];     // [2][2][BN][32]
    __shared__ float    inv_denom[256];

    const int tid  = threadIdx.x;
    const int wv   = tid >> 6;
    const int lane = tid & 63;
    const int quad = lane >> 4;
    const int l15  = lane & 15;
    const int wm   = wv >> 2;   // 0..1  (wave row-block)
    const int wn   = wv & 3;    // 0..3  (wave col-block)
    const int z    = blockIdx.z;

    A += (long long)z * sAz;
    B += (long long)z * sBz;
    C += (long long)z * sCz;

    const int m0 = blockIdx.x * 256;
    const int n0 = blockIdx.y * BN;

    if (EPI == 4) {
        if (tid < 256) {
            const float* gp = gsum + (long long)z * 32768 + (m0 + tid) * 16;
            float s = 0.f;
#pragma unroll
            for (int t = 0; t < 16; ++t) s += gp[t];
            inv_denom[tid] = 1.f / s;
        }
        // visibility via prologue barrier
    }

    // ---- staging geometry: thread covers 16B slot tid (rows 0..127) and,
    // for 256-row granules, slot tid+512 (rows 128..255, same k-chunk).
    const int r  = tid >> 2;                          // 0..127
    const int ca = (tid & 3) ^ ((tid >> 3) & 3);      // global k-chunk held
    const uint16_t* aS = A + (long long)(m0 + r) * lda + ca * 8;
    const uint16_t* bS = B + (long long)(n0 + r) * ldb + ca * 8;
    const int dOf = wv * 1024;   // wave-uniform LDS dest (HW adds lane*16)

    auto STAGE_A = [&](int kt, int h, int sl) {
        const uint16_t* s = aS + kt * 64 + h * 32;
        char* d = (char*)ldsA + sl * 32768 + h * 16384 + dOf;
        gload_lds16(s, d);
        gload_lds16(s + (long long)128 * lda, d + 8192);
    };
    auto STAGE_B = [&](int kt, int h, int sl) {
        const uint16_t* s = bS + kt * 64 + h * 32;
        char* d = (char*)ldsB + sl * BSLOT + h * BKH + dOf;
        gload_lds16(s, d);
        if (LB == 2) gload_lds16(s + (long long)128 * ldb, d + 8192);
    };

    // ---- frag-read geometry (chunk swizzle index = quad ^ ((l15>>1)&3))
    const int csw  = ((quad ^ (l15 >> 1)) & 3) * 16;
    const int aOff = (wm * 128 + l15) * 64 + csw;
    const int bOff = (wn * (BN / 4) + l15) * 64 + csw;

    f32x4_t acc[8][NF];
#pragma unroll
    for (int i = 0; i < 8; ++i)
#pragma unroll
        for (int j = 0; j < NF; ++j) acc[i][j] = f32x4_t{0.f, 0.f, 0.f, 0.f};

    const int NT = K >> 6;

    if constexpr (NF == 4) {
        // ---- prologue: tile0 complete + tile1 {B-kh0, A-kh0, B-kh1}
        STAGE_B(0, 0, 0); STAGE_A(0, 0, 0); STAGE_B(0, 1, 0); STAGE_A(0, 1, 0);
        STAGE_B(1, 0, 1); STAGE_A(1, 0, 1); STAGE_B(1, 1, 1);
        asm volatile("s_waitcnt vmcnt(6)" ::: "memory");
        BAR();

        for (int t = 0; t < NT; ++t) {
            const int sl = t & 1;
            const int so = sl ^ 1;
            const int t1 = (t + 1 < NT) ? t + 1 : 0;   // wrap: keeps vmcnt counts
            const int t2 = (t + 2 < NT) ? t + 2 : 0;   // uniform; wraps never read
            const char* Ab = (const char*)ldsA + sl * 32768;
            const char* Bb = (const char*)ldsB + sl * BSLOT;

            bf16x8_t af[4], bfv[4];

            // -- phase 1: (qm0, kh0) + read B-kh0; stage A-kh1(t+1) -> other slot
#pragma unroll
            for (int i = 0; i < 4; ++i)
                af[i] = *(const bf16x8_t*)(Ab + i * 1024 + aOff);
#pragma unroll
            for (int j = 0; j < 4; ++j)
                bfv[j] = *(const bf16x8_t*)(Bb + j * 1024 + bOff);
            STAGE_A(t1, 1, so);
            BAR(); WLGKM();
            __builtin_amdgcn_s_setprio(1);
#pragma unroll
            for (int i = 0; i < 4; ++i)
#pragma unroll
                for (int j = 0; j < 4; ++j)
                    acc[i][j] = __builtin_amdgcn_mfma_f32_16x16x32_bf16(
                        af[i], bfv[j], acc[i][j], 0, 0, 0);
            __builtin_amdgcn_s_setprio(0);
            BAR();

            // -- phase 2: (qm1, kh0); stage B-kh0(t+2) -> this slot
#pragma unroll
            for (int i = 0; i < 4; ++i)
                af[i] = *(const bf16x8_t*)(Ab + 4096 + i * 1024 + aOff);
            STAGE_B(t2, 0, sl);
            BAR(); WLGKM();
            __builtin_amdgcn_s_setprio(1);
#pragma unroll
            for (int i = 0; i < 4; ++i)
#pragma unroll
                for (int j = 0; j < 4; ++j)
                    acc[4 + i][j] = __builtin_amdgcn_mfma_f32_16x16x32_bf16(
                        af[i], bfv[j], acc[4 + i][j], 0, 0, 0);
            __builtin_amdgcn_s_setprio(0);
            BAR();

            // -- phase 3: (qm0, kh1) + read B-kh1; stage A-kh0(t+2) -> this slot
#pragma unroll
            for (int i = 0; i < 4; ++i)
                af[i] = *(const bf16x8_t*)(Ab + 16384 + i * 1024 + aOff);
#pragma unroll
            for (int j = 0; j < 4; ++j)
                bfv[j] = *(const bf16x8_t*)(Bb + BKH + j * 1024 + bOff);
            STAGE_A(t2, 0, sl);
            BAR(); WLGKM();
            __builtin_amdgcn_s_setprio(1);
#pragma unroll
            for (int i = 0; i < 4; ++i)
#pragma unroll
                for (int j = 0; j < 4; ++j)
                    acc[i][j] = __builtin_amdgcn_mfma_f32_16x16x32_bf16(
                        af[i], bfv[j], acc[i][j], 0, 0, 0);
            __builtin_amdgcn_s_setprio(0);
            BAR();

            // -- phase 4: (qm1, kh1); stage B-kh1(t+2) -> this slot; counted vmcnt
#pragma unroll
            for (int i = 0; i < 4; ++i)
                af[i] = *(const bf16x8_t*)(Ab + 16384 + 4096 + i * 1024 + aOff);
            STAGE_B(t2, 1, sl);
            BAR(); WLGKM();
            __builtin_amdgcn_s_setprio(1);
#pragma unroll
            for (int i = 0; i < 4; ++i)
#pragma unroll
                for (int j = 0; j < 4; ++j)
                    acc[4 + i][j] = __builtin_amdgcn_mfma_f32_16x16x32_bf16(
                        af[i], bfv[j], acc[4 + i][j], 0, 0, 0);
            __builtin_amdgcn_s_setprio(0);
            asm volatile("s_waitcnt vmcnt(6)" ::: "memory");
            BAR();
        }
    } else {
        // ---- NF == 2: 2 phases per K-tile, 16 MFMA per phase.
        static_assert(NF != 2 || LB == 1, "pair = 3 loads assumes LB==1");
        // prologue: pairs 0 (t0,k0), 1 (t0,k1), 2 (t1,k0)
        STAGE_A(0, 0, 0); STAGE_B(0, 0, 0);
        STAGE_A(0, 1, 0); STAGE_B(0, 1, 0);
        STAGE_A(1, 0, 1); STAGE_B(1, 0, 1);
        asm volatile("s_waitcnt vmcnt(6)" ::: "memory");  // pairs 1,2 in flight
        BAR();

        for (int t = 0; t < NT; ++t) {
            const int sl = t & 1;
            const int so = sl ^ 1;
            const int t1 = (t + 1 < NT) ? t + 1 : 0;
            const int t2 = (t + 2 < NT) ? t + 2 : 0;
            const char* Ab = (const char*)ldsA + sl * 32768;
            const char* Bb = (const char*)ldsB + sl * BSLOT;

            bf16x8_t af[8], bfv[2];

            // -- phase A: kh0; stage pair (t+1, kh1) -> other slot
#pragma unroll
            for (int i = 0; i < 8; ++i)
                af[i] = *(const bf16x8_t*)(Ab + i * 1024 + aOff);
#pragma unroll
            for (int j = 0; j < 2; ++j)
                bfv[j] = *(const bf16x8_t*)(Bb + j * 1024 + bOff);
            STAGE_A(t1, 1, so); STAGE_B(t1, 1, so);
            BAR(); WLGKM();
            __builtin_amdgcn_s_setprio(1);
#pragma unroll
            for (int i = 0; i < 8; ++i)
#pragma unroll
                for (int j = 0; j < 2; ++j)
                    acc[i][j] = __builtin_amdgcn_mfma_f32_16x16x32_bf16(
                        af[i], bfv[j], acc[i][j], 0, 0, 0);
            __builtin_amdgcn_s_setprio(0);
            asm volatile("s_waitcnt vmcnt(6)" ::: "memory");
            BAR();

            // -- phase B: kh1; stage pair (t+2, kh0) -> this slot
#pragma unroll
            for (int i = 0; i < 8; ++i)
                af[i] = *(const bf16x8_t*)(Ab + 16384 + i * 1024 + aOff);
#pragma unroll
            for (int j = 0; j < 2; ++j)
                bfv[j] = *(const bf16x8_t*)(Bb + BKH + j * 1024 + bOff);
            STAGE_A(t2, 0, sl); STAGE_B(t2, 0, sl);
            BAR(); WLGKM();
            __builtin_amdgcn_s_setprio(1);
#pragma unroll
            for (int i = 0; i < 8; ++i)
#pragma unroll
                for (int j = 0; j < 2; ++j)
                    acc[i][j] = __builtin_amdgcn_mfma_f32_16x16x32_bf16(
                        af[i], bfv[j], acc[i][j], 0, 0, 0);
            __builtin_amdgcn_s_setprio(0);
            asm volatile("s_waitcnt vmcnt(6)" ::: "memory");
            BAR();
        }
    }

    // ---- epilogue (C/D layout: col = lane&15, row = quad*4 + reg)
    if (EPI == 1 || EPI == 2) {
        const float* bias = (z == 0) ? bias0 : bias1;
#pragma unroll
        for (int fi = 0; fi < 8; ++fi) {
            const int mb = m0 + wm * 128 + fi * 16 + quad * 4;
            float rb[4];
            if (EPI == 2) {
#pragma unroll
                for (int rr = 0; rr < 4; ++rr) rb[rr] = bias[mb + rr];
            }
#pragma unroll
            for (int fj = 0; fj < NF; ++fj) {
                const int n = n0 + wn * (BN / 4) + fj * 16 + l15;
                const float cb = (EPI == 1) ? bias[n] : 0.f;
#pragma unroll
                for (int rr = 0; rr < 4; ++rr) {
                    const float vv = acc[fi][fj][rr] + ((EPI == 1) ? cb : rb[rr]);
                    if (sizeof(OutT) == 1)
                        ((uint8_t*)C)[(long long)(mb + rr) * ldc + n] = f2fp8(vv);
                    else
                        ((uint16_t*)C)[(long long)(mb + rr) * ldc + n] = f2bf(vv);
                }
            }
        }
    } else {  // EPI == 4
#pragma unroll
        for (int fi = 0; fi < 8; ++fi) {
            const int rl = wm * 128 + fi * 16 + quad * 4;
            const int mb = m0 + rl;
#pragma unroll
            for (int fj = 0; fj < NF; ++fj) {
                const int n = n0 + wn * (BN / 4) + fj * 16 + l15;
#pragma unroll
                for (int rr = 0; rr < 4; ++rr)
                    ((float*)C)[(long long)(mb + rr) * ldc + n] =
                        acc[fi][fj][rr] * inv_denom[rl + rr];
            }
        }
    }
}

// ---------------------------------------------------------------------------
// fp8 score GEMM: P~ = exp((Q K^T)/32), MX-fp8 MFMA K=128 with unit scales.
// (unchanged, r5-verified)
// ---------------------------------------------------------------------------
__global__ __launch_bounds__(256, 3) void score_f8(
    const uint8_t* __restrict__ Qf8, const uint8_t* __restrict__ Kf8,
    uint16_t* __restrict__ P, float* __restrict__ gsum, float alpha)
{
    __shared__ uint8_t ldsA[128 * 128];
    __shared__ uint8_t ldsB[128 * 128];

    const int tid  = threadIdx.x;
    const int wave = tid >> 6;
    const int lane = tid & 63;
    const int quad = lane >> 4;
    const int l15  = lane & 15;
    const int z    = blockIdx.z;

    const uint8_t* A = Qf8 + (long long)z * 2097152;
    const uint8_t* B = Kf8 + (long long)z * 2097152;
    uint16_t* C = P + (long long)z * 4194304;

    const int m0 = blockIdx.x * 128;
    const int n0 = blockIdx.y * 128;

    const uint8_t* gA[4];
    const uint8_t* gB[4];
    uint8_t* lA[4];
    uint8_t* lB[4];
#pragma unroll
    for (int c = 0; c < 4; ++c) {
        const int s   = (c * 4 + wave) * 64 + lane;
        const int r   = s >> 3;
        const int col = ((s & 7) ^ (r & 7)) * 16;
        gA[c] = A + (long long)(m0 + r) * 1024 + col;
        gB[c] = B + (long long)(n0 + r) * 1024 + col;
        lA[c] = ldsA + (c * 4 + wave) * 1024;
        lB[c] = ldsB + (c * 4 + wave) * 1024;
    }

    const int m_off = (wave & 1) * 64;
    const int n_off = (wave >> 1) * 64;

    f32x4_t acc[4][4];
#pragma unroll
    for (int i = 0; i < 4; ++i)
#pragma unroll
        for (int j = 0; j < 4; ++j)
            acc[i][j] = f32x4_t{0.f, 0.f, 0.f, 0.f};

    const int h0 = quad * 2;
    const int h1 = quad * 2 + 1;

    for (int k0 = 0; k0 < 1024; k0 += 128) {
#pragma unroll
        for (int c = 0; c < 4; ++c) gload_lds16(gA[c], lA[c]);
#pragma unroll
        for (int c = 0; c < 4; ++c) gload_lds16(gB[c], lB[c]);
#pragma unroll
        for (int c = 0; c < 4; ++c) { gA[c] += 128; gB[c] += 128; }
        __syncthreads();

        i32x8_t af[4], bfr[4];
#pragma unroll
        for (int i = 0; i < 4; ++i) {
            const int m = m_off + i * 16 + l15;
            const int sw = m & 7;
            const i32x4_t lo = *(const i32x4_t*)(ldsA + m * 128 + (h0 ^ sw) * 16);
            const i32x4_t hi = *(const i32x4_t*)(ldsA + m * 128 + (h1 ^ sw) * 16);
            af[i] = i32x8_t{lo[0], lo[1], lo[2], lo[3], hi[0], hi[1], hi[2], hi[3]};
        }
#pragma unroll
        for (int j = 0; j < 4; ++j) {
            const int n = n_off + j * 16 + l15;
            const int sw = n & 7;
            const i32x4_t lo = *(const i32x4_t*)(ldsB + n * 128 + (h0 ^ sw) * 16);
            const i32x4_t hi = *(const i32x4_t*)(ldsB + n * 128 + (h1 ^ sw) * 16);
            bfr[j] = i32x8_t{lo[0], lo[1], lo[2], lo[3], hi[0], hi[1], hi[2], hi[3]};
        }
#pragma unroll
        for (int i = 0; i < 4; ++i)
#pragma unroll
            for (int j = 0; j < 4; ++j)
                acc[i][j] = __builtin_amdgcn_mfma_scale_f32_16x16x128_f8f6f4(
                    af[i], bfr[j], acc[i][j],
                    0, 0,
                    0, 0x7f7f7f7f,
                    0, 0x7f7f7f7f);
        __syncthreads();
    }

    float rs[4][4];
#pragma unroll
    for (int i = 0; i < 4; ++i)
#pragma unroll
        for (int r = 0; r < 4; ++r) rs[i][r] = 0.f;
#pragma unroll
    for (int i = 0; i < 4; ++i) {
        const int mb = m0 + m_off + i * 16 + quad * 4;
#pragma unroll
        for (int j = 0; j < 4; ++j) {
            const int n = n0 + n_off + j * 16 + l15;
#pragma unroll
            for (int r = 0; r < 4; ++r) {
                const float e = exp2f(acc[i][j][r] * alpha);
                rs[i][r] += e;
                C[(long long)(mb + r) * 2048 + n] = f2bf(e);
            }
        }
    }
#pragma unroll
    for (int m = 1; m < 16; m <<= 1)
#pragma unroll
        for (int i = 0; i < 4; ++i)
#pragma unroll
            for (int r = 0; r < 4; ++r)
                rs[i][r] += __shfl_xor(rs[i][r], m);
    float* lp = (float*)ldsA;
    if (l15 == 0) {
#pragma unroll
        for (int i = 0; i < 4; ++i)
#pragma unroll
            for (int r = 0; r < 4; ++r)
                lp[wave * 64 + i * 16 + quad * 4 + r] = rs[i][r];
    }
    __syncthreads();
    if (tid < 128) {
        const float s = lp[(tid >> 6) * 64 + (tid & 63)] +
                        lp[((tid >> 6) + 2) * 64 + (tid & 63)];
        gsum[(long long)z * 32768 + (m0 + tid) * 16 + blockIdx.y] = s;
    }
}

// fp32 -> bf16 for x (blocks 0..8191) and Wq/Wk/Wv (blocks 8192..11263).
__global__ void cvt_all(const float* __restrict__ x,
                        const float* __restrict__ Wq, const float* __restrict__ Wk,
                        const float* __restrict__ Wv,
                        uint16_t* __restrict__ x_bf, uint16_t* __restrict__ w_bf) {
    const int b = blockIdx.x;
    const float* src;
    uint16_t* dst;
    int i;
    if (b < 8192) {
        src = x; dst = x_bf; i = b * 256 + threadIdx.x;
    } else {
        const int wz = (b - 8192) >> 10;
        const int rb = (b - 8192) & 1023;
        src = (wz == 0) ? Wq : (wz == 1) ? Wk : Wv;
        dst = w_bf + (long long)wz * 1048576;
        i = rb * 256 + threadIdx.x;
    }
    const float4 f = ((const float4*)src)[i];
    ushort4 o;
    o.x = f2bf(f.x); o.y = f2bf(f.y); o.z = f2bf(f.z); o.w = f2bf(f.w);
    ((ushort4*)dst)[i] = o;
}

extern "C" void kernel_launch(void* const* d_in, const int* in_sizes, int n_in,
                              void* d_out, int out_size, void* d_ws, size_t ws_size,
                              hipStream_t stream) {
    const float* x  = (const float*)d_in[0];
    const float* Wq = (const float*)d_in[1];
    const float* bq = (const float*)d_in[2];
    const float* Wk = (const float*)d_in[3];
    const float* bk = (const float*)d_in[4];
    const float* Wv = (const float*)d_in[5];
    const float* bv = (const float*)d_in[6];
    float* out = (float*)d_out;

    char* w = (char*)d_ws;
    uint16_t* x_bf = (uint16_t*)(w);
    float*    gsum = (float*)(w);                 // overlays dead x_bf
    uint16_t* w_bf = (uint16_t*)(w + 16777216);
    uint8_t*  Qf8  = (uint8_t*)(w + 23068672);
    uint8_t*  Kf8  = (uint8_t*)(w + 31457280);
    uint16_t* Vt   = (uint16_t*)(w + 39845888);
    uint16_t* Pb   = (uint16_t*)(w + 56623104);

    // 1) fp32 -> bf16 conversions (x + all three W)
    cvt_all<<<11264, 256, 0, stream>>>(x, Wq, Wk, Wv, x_bf, w_bf);

    // 2) Q,K = x @ W^T + b  [8192,1024] fp8 out.  256x256 tiles: (32,4,2)=256 wg
    gemm8p<256, 1, uint8_t><<<dim3(32, 4, 2), 512, 0, stream>>>(
        x_bf, 1024, 0LL,
        w_bf, 1024, 1048576LL,
        Qf8, 1024, 8388608LL,
        bq, bk, nullptr, 1024);

    // 2b) Vt[e, b*2048+s] = Wv x^T + bv  [1024,8192].  256x128: (4,64,1)=256 wg
    gemm8p<128, 2, uint16_t><<<dim3(4, 64, 1), 512, 0, stream>>>(
        w_bf + 2097152, 1024, 0LL,
        x_bf, 1024, 0LL,
        Vt, 8192, 0LL,
        bv, bv, nullptr, 1024);

    // 3) P~_b = exp((Q_b K_b^T)/32) via MX-fp8 K=128; alpha = (1/32)*log2(e)
    score_f8<<<dim3(16, 16, 4), 256, 0, stream>>>(
        Qf8, Kf8, Pb, gsum, 0.045084222f);

    // 4) O_b = (P~_b @ V_b) / denom : fp32 out.  256x128: (8,8,4)=256 wg
    gemm8p<128, 4, float><<<dim3(8, 8, 4), 512, 0, stream>>>(
        Pb, 2048, 4194304LL,
        Vt, 8192, 2048LL,
        out, 1024, 2097152LL,
        nullptr, nullptr, gsum, 2048);
}

// Round 4
// 250.855 us; speedup vs baseline: 1.0389x; 1.0028x over previous
//
#include <hip/hip_runtime.h>
#include <cstdint>

// B=4, S=2048, D=1024.  M_qkv = B*S = 8192.
// ws layout (bytes):
//   x_bf  @ 0        : 16,777,216  bf16 [8192][1024] (dead after Vt-proj;
//                      gsum f32[8192][16] overlays @0, written by score)
//   w_bf  @ 16777216 :  6,291,456  bf16 Wq,Wk,Wv each [1024][1024]
//   Qf8   @ 23068672 :  8,388,608  fp8 e4m3 [8192][1024]
//   Kf8   @ 31457280 :  8,388,608  fp8 e4m3 [8192][1024]
//   Vt    @ 39845888 : 16,777,216  bf16 [1024][8192], col = b*2048+s
//   P~    @ 56623104 : 33,554,432  bf16 [4][2048][2048] = exp(s/32), unnorm.

typedef __bf16 bf16x8_t __attribute__((ext_vector_type(8)));
typedef float  f32x4_t  __attribute__((ext_vector_type(4)));
typedef int    i32x8_t  __attribute__((ext_vector_type(8)));
typedef int    i32x4_t  __attribute__((ext_vector_type(4)));

__device__ __forceinline__ uint16_t f2bf(float f) {
    union { float f; uint32_t u; } v; v.f = f;
    return (uint16_t)((v.u + 0x7fffu + ((v.u >> 16) & 1u)) >> 16);  // RNE
}

// fp32 -> OCP e4m3fn, RNE.  Values here are |f| <~ 8, well inside range.
__device__ __forceinline__ uint8_t f2fp8(float f) {
    union { float f; uint32_t u; } v; v.f = f;
    const uint32_t sgn = (v.u >> 31) << 7;
    const uint32_t mag = v.u & 0x7fffffffu;
    uint32_t out;
    if (mag < 0x3c800000u) {                       // |f| < 2^-6: subnormal
        out = (uint32_t)__builtin_rintf(__builtin_fabsf(f) * 512.0f); // 0..8
    } else {
        uint32_t t = mag + 0x7ffffu + ((mag >> 20) & 1u);  // RNE at bit 20
        out = (t >> 20) - 960u;                            // (E<<3|m) - (120<<3)
        if (out > 0x7eu) out = 0x7eu;                      // clamp to 448
    }
    return (uint8_t)(sgn | out);
}

__device__ __forceinline__ void gload_lds16(const void* g, void* lds) {
    __builtin_amdgcn_global_load_lds(
        (const __attribute__((address_space(1))) void*)g,
        (__attribute__((address_space(3))) void*)lds, 16, 0, 0);
}

// Raw barriers: no compiler-inserted vmcnt(0) drain (that drain is the m97
// ~900TF ceiling).  "memory" clobber = compiler-level fence so LDS reads /
// LDS-DMA issues cannot migrate across phases.
#define BAR()   asm volatile("s_barrier" ::: "memory")
#define WLGKM() asm volatile("s_waitcnt lgkmcnt(0)" ::: "memory")

// ---------------------------------------------------------------------------
// 256x128 bf16 B^T GEMM, NF==2 2-phase schedule ONLY (R3-proven: PV and Vt
// left the top-5; the co-compiled NF==4 branch regressed QK to 81us with
// MfmaUtil 16% despite 0 conflicts -> rule-#19 codegen perturbation.  This
// round: single code path, QK re-tiled to BN=128.)
//
// BK=64, 512 thr = 2x4 waves.  LDS per matrix: [2 slot][2 kh][rows][32 k].
// Chunk swizzle: 16B chunk p of row r holds global chunk p ^ ((r>>1)&3).
// Any 8 consecutive lanes of a frag ds_read_b128 hit bank-groups
// {(l15&1)*4 + (quad^((l15>>1)&3))} = a permutation of 0..7 -> conflict-
// free (verified: SQ_LDS_BANK_CONFLICT 5.24M -> 0 in R3).
//
// 2 phases per K-tile, phase=kh, all 8 m-frags x 2 n-frags = 16 MFMA each.
// Pair-granule pipeline: phase j reads pair j, stages pair j+3 (pair =
// {A,B} of one kh = 3 loads); vmcnt(6) per phase keeps pairs j+1, j+2 in
// flight.  Pair j+3 overwrites the (slot,kh) of pair j-1, whose ds_reads
// drained at phase j-1's lgkmcnt(0) before its end-barrier.
//
// EPI: 1 = +bias[n], fp8 out (Q/K)   2 = +bias[m], bf16 out (Vt)
//      4 = acc * 1/sum16(gsum_row), fp32 out (PV)
// ---------------------------------------------------------------------------
template <int EPI, typename OutT>
__global__ __launch_bounds__(512, 2) void gemm2p(
    const uint16_t* __restrict__ A, int lda, long long sAz,
    const uint16_t* __restrict__ B, int ldb, long long sBz,
    OutT* __restrict__ C, int ldc, long long sCz,
    const float* __restrict__ bias0, const float* __restrict__ bias1,
    const float* __restrict__ gsum, int K)
{
    constexpr int BN = 128;

    __shared__ uint16_t ldsA[32768];        // 64 KiB: [2][2][256][32]
    __shared__ uint16_t ldsB[16384];        // 32 KiB: [2][2][128][32]
    __shared__ float    inv_denom[256];

    const int tid  = threadIdx.x;
    const int wv   = tid >> 6;
    const int lane = tid & 63;
    const int quad = lane >> 4;
    const int l15  = lane & 15;
    const int wm   = wv >> 2;   // 0..1  (wave row-block)
    const int wn   = wv & 3;    // 0..3  (wave col-block)
    const int z    = blockIdx.z;

    A += (long long)z * sAz;
    B += (long long)z * sBz;
    C += (long long)z * sCz;

    const int m0 = blockIdx.x * 256;
    const int n0 = blockIdx.y * BN;

    if (EPI == 4) {
        if (tid < 256) {
            const float* gp = gsum + (long long)z * 32768 + (m0 + tid) * 16;
            float s = 0.f;
#pragma unroll
            for (int t = 0; t < 16; ++t) s += gp[t];
            inv_denom[tid] = 1.f / s;
        }
        // visibility via prologue barrier
    }

    // ---- staging geometry: thread covers 16B slot tid (rows 0..127); A's
    // second load covers rows 128..255 (same k-chunk).
    const int r  = tid >> 2;                          // 0..127
    const int ca = (tid & 3) ^ ((tid >> 3) & 3);      // global k-chunk held
    const uint16_t* aS = A + (long long)(m0 + r) * lda + ca * 8;
    const uint16_t* bS = B + (long long)(n0 + r) * ldb + ca * 8;
    const int dOf = wv * 1024;   // wave-uniform LDS dest (HW adds lane*16)

    auto STAGE_A = [&](int kt, int h, int sl) {
        const uint16_t* s = aS + kt * 64 + h * 32;
        char* d = (char*)ldsA + sl * 32768 + h * 16384 + dOf;
        gload_lds16(s, d);
        gload_lds16(s + (long long)128 * lda, d + 8192);
    };
    auto STAGE_B = [&](int kt, int h, int sl) {
        const uint16_t* s = bS + kt * 64 + h * 32;
        char* d = (char*)ldsB + sl * 16384 + h * 8192 + dOf;
        gload_lds16(s, d);
    };

    // ---- frag-read geometry (chunk swizzle index = quad ^ ((l15>>1)&3))
    const int csw  = ((quad ^ (l15 >> 1)) & 3) * 16;
    const int aOff = (wm * 128 + l15) * 64 + csw;
    const int bOff = (wn * 32 + l15) * 64 + csw;

    f32x4_t acc[8][2];
#pragma unroll
    for (int i = 0; i < 8; ++i)
#pragma unroll
        for (int j = 0; j < 2; ++j) acc[i][j] = f32x4_t{0.f, 0.f, 0.f, 0.f};

    const int NT = K >> 6;

    // prologue: pairs 0 (t0,k0), 1 (t0,k1), 2 (t1,k0); pair = 3 loads
    STAGE_A(0, 0, 0); STAGE_B(0, 0, 0);
    STAGE_A(0, 1, 0); STAGE_B(0, 1, 0);
    STAGE_A(1, 0, 1); STAGE_B(1, 0, 1);
    asm volatile("s_waitcnt vmcnt(6)" ::: "memory");  // pairs 1,2 in flight
    BAR();

    for (int t = 0; t < NT; ++t) {
        const int sl = t & 1;
        const int so = sl ^ 1;
        const int t1 = (t + 1 < NT) ? t + 1 : 0;   // wrap keeps vmcnt counts
        const int t2 = (t + 2 < NT) ? t + 2 : 0;   // uniform; wraps never read
        const char* Ab = (const char*)ldsA + sl * 32768;
        const char* Bb = (const char*)ldsB + sl * 16384;

        bf16x8_t af[8], bfv[2];

        // -- phase A: kh0; stage pair (t+1, kh1) -> other slot
#pragma unroll
        for (int i = 0; i < 8; ++i)
            af[i] = *(const bf16x8_t*)(Ab + i * 1024 + aOff);
#pragma unroll
        for (int j = 0; j < 2; ++j)
            bfv[j] = *(const bf16x8_t*)(Bb + j * 1024 + bOff);
        STAGE_A(t1, 1, so); STAGE_B(t1, 1, so);
        BAR(); WLGKM();
        __builtin_amdgcn_s_setprio(1);
#pragma unroll
        for (int i = 0; i < 8; ++i)
#pragma unroll
            for (int j = 0; j < 2; ++j)
                acc[i][j] = __builtin_amdgcn_mfma_f32_16x16x32_bf16(
                    af[i], bfv[j], acc[i][j], 0, 0, 0);
        __builtin_amdgcn_s_setprio(0);
        asm volatile("s_waitcnt vmcnt(6)" ::: "memory");
        BAR();

        // -- phase B: kh1; stage pair (t+2, kh0) -> this slot
#pragma unroll
        for (int i = 0; i < 8; ++i)
            af[i] = *(const bf16x8_t*)(Ab + 16384 + i * 1024 + aOff);
#pragma unroll
        for (int j = 0; j < 2; ++j)
            bfv[j] = *(const bf16x8_t*)(Bb + 8192 + j * 1024 + bOff);
        STAGE_A(t2, 0, sl); STAGE_B(t2, 0, sl);
        BAR(); WLGKM();
        __builtin_amdgcn_s_setprio(1);
#pragma unroll
        for (int i = 0; i < 8; ++i)
#pragma unroll
            for (int j = 0; j < 2; ++j)
                acc[i][j] = __builtin_amdgcn_mfma_f32_16x16x32_bf16(
                    af[i], bfv[j], acc[i][j], 0, 0, 0);
        __builtin_amdgcn_s_setprio(0);
        asm volatile("s_waitcnt vmcnt(6)" ::: "memory");
        BAR();
    }

    // ---- epilogue (C/D layout: col = lane&15, row = quad*4 + reg)
    if (EPI == 1 || EPI == 2) {
        const float* bias = (z == 0) ? bias0 : bias1;
#pragma unroll
        for (int fi = 0; fi < 8; ++fi) {
            const int mb = m0 + wm * 128 + fi * 16 + quad * 4;
            float rb[4];
            if (EPI == 2) {
#pragma unroll
                for (int rr = 0; rr < 4; ++rr) rb[rr] = bias[mb + rr];
            }
#pragma unroll
            for (int fj = 0; fj < 2; ++fj) {
                const int n = n0 + wn * 32 + fj * 16 + l15;
                const float cb = (EPI == 1) ? bias[n] : 0.f;
#pragma unroll
                for (int rr = 0; rr < 4; ++rr) {
                    const float vv = acc[fi][fj][rr] + ((EPI == 1) ? cb : rb[rr]);
                    if (sizeof(OutT) == 1)
                        ((uint8_t*)C)[(long long)(mb + rr) * ldc + n] = f2fp8(vv);
                    else
                        ((uint16_t*)C)[(long long)(mb + rr) * ldc + n] = f2bf(vv);
                }
            }
        }
    } else {  // EPI == 4
#pragma unroll
        for (int fi = 0; fi < 8; ++fi) {
            const int rl = wm * 128 + fi * 16 + quad * 4;
            const int mb = m0 + rl;
#pragma unroll
            for (int fj = 0; fj < 2; ++fj) {
                const int n = n0 + wn * 32 + fj * 16 + l15;
#pragma unroll
                for (int rr = 0; rr < 4; ++rr)
                    ((float*)C)[(long long)(mb + rr) * ldc + n] =
                        acc[fi][fj][rr] * inv_denom[rl + rr];
            }
        }
    }
}

// ---------------------------------------------------------------------------
// fp8 score GEMM: P~ = exp((Q K^T)/32), MX-fp8 MFMA K=128 with unit scales.
// (unchanged, r5-verified)
// ---------------------------------------------------------------------------
__global__ __launch_bounds__(256, 3) void score_f8(
    const uint8_t* __restrict__ Qf8, const uint8_t* __restrict__ Kf8,
    uint16_t* __restrict__ P, float* __restrict__ gsum, float alpha)
{
    __shared__ uint8_t ldsA[128 * 128];
    __shared__ uint8_t ldsB[128 * 128];

    const int tid  = threadIdx.x;
    const int wave = tid >> 6;
    const int lane = tid & 63;
    const int quad = lane >> 4;
    const int l15  = lane & 15;
    const int z    = blockIdx.z;

    const uint8_t* A = Qf8 + (long long)z * 2097152;
    const uint8_t* B = Kf8 + (long long)z * 2097152;
    uint16_t* C = P + (long long)z * 4194304;

    const int m0 = blockIdx.x * 128;
    const int n0 = blockIdx.y * 128;

    const uint8_t* gA[4];
    const uint8_t* gB[4];
    uint8_t* lA[4];
    uint8_t* lB[4];
#pragma unroll
    for (int c = 0; c < 4; ++c) {
        const int s   = (c * 4 + wave) * 64 + lane;
        const int r   = s >> 3;
        const int col = ((s & 7) ^ (r & 7)) * 16;
        gA[c] = A + (long long)(m0 + r) * 1024 + col;
        gB[c] = B + (long long)(n0 + r) * 1024 + col;
        lA[c] = ldsA + (c * 4 + wave) * 1024;
        lB[c] = ldsB + (c * 4 + wave) * 1024;
    }

    const int m_off = (wave & 1) * 64;
    const int n_off = (wave >> 1) * 64;

    f32x4_t acc[4][4];
#pragma unroll
    for (int i = 0; i < 4; ++i)
#pragma unroll
        for (int j = 0; j < 4; ++j)
            acc[i][j] = f32x4_t{0.f, 0.f, 0.f, 0.f};

    const int h0 = quad * 2;
    const int h1 = quad * 2 + 1;

    for (int k0 = 0; k0 < 1024; k0 += 128) {
#pragma unroll
        for (int c = 0; c < 4; ++c) gload_lds16(gA[c], lA[c]);
#pragma unroll
        for (int c = 0; c < 4; ++c) gload_lds16(gB[c], lB[c]);
#pragma unroll
        for (int c = 0; c < 4; ++c) { gA[c] += 128; gB[c] += 128; }
        __syncthreads();

        i32x8_t af[4], bfr[4];
#pragma unroll
        for (int i = 0; i < 4; ++i) {
            const int m = m_off + i * 16 + l15;
            const int sw = m & 7;
            const i32x4_t lo = *(const i32x4_t*)(ldsA + m * 128 + (h0 ^ sw) * 16);
            const i32x4_t hi = *(const i32x4_t*)(ldsA + m * 128 + (h1 ^ sw) * 16);
            af[i] = i32x8_t{lo[0], lo[1], lo[2], lo[3], hi[0], hi[1], hi[2], hi[3]};
        }
#pragma unroll
        for (int j = 0; j < 4; ++j) {
            const int n = n_off + j * 16 + l15;
            const int sw = n & 7;
            const i32x4_t lo = *(const i32x4_t*)(ldsB + n * 128 + (h0 ^ sw) * 16);
            const i32x4_t hi = *(const i32x4_t*)(ldsB + n * 128 + (h1 ^ sw) * 16);
            bfr[j] = i32x8_t{lo[0], lo[1], lo[2], lo[3], hi[0], hi[1], hi[2], hi[3]};
        }
#pragma unroll
        for (int i = 0; i < 4; ++i)
#pragma unroll
            for (int j = 0; j < 4; ++j)
                acc[i][j] = __builtin_amdgcn_mfma_scale_f32_16x16x128_f8f6f4(
                    af[i], bfr[j], acc[i][j],
                    0, 0,
                    0, 0x7f7f7f7f,
                    0, 0x7f7f7f7f);
        __syncthreads();
    }

    float rs[4][4];
#pragma unroll
    for (int i = 0; i < 4; ++i)
#pragma unroll
        for (int r = 0; r < 4; ++r) rs[i][r] = 0.f;
#pragma unroll
    for (int i = 0; i < 4; ++i) {
        const int mb = m0 + m_off + i * 16 + quad * 4;
#pragma unroll
        for (int j = 0; j < 4; ++j) {
            const int n = n0 + n_off + j * 16 + l15;
#pragma unroll
            for (int r = 0; r < 4; ++r) {
                const float e = exp2f(acc[i][j][r] * alpha);
                rs[i][r] += e;
                C[(long long)(mb + r) * 2048 + n] = f2bf(e);
            }
        }
    }
#pragma unroll
    for (int m = 1; m < 16; m <<= 1)
#pragma unroll
        for (int i = 0; i < 4; ++i)
#pragma unroll
            for (int r = 0; r < 4; ++r)
                rs[i][r] += __shfl_xor(rs[i][r], m);
    float* lp = (float*)ldsA;
    if (l15 == 0) {
#pragma unroll
        for (int i = 0; i < 4; ++i)
#pragma unroll
            for (int r = 0; r < 4; ++r)
                lp[wave * 64 + i * 16 + quad * 4 + r] = rs[i][r];
    }
    __syncthreads();
    if (tid < 128) {
        const float s = lp[(tid >> 6) * 64 + (tid & 63)] +
                        lp[((tid >> 6) + 2) * 64 + (tid & 63)];
        gsum[(long long)z * 32768 + (m0 + tid) * 16 + blockIdx.y] = s;
    }
}

// fp32 -> bf16 for x (blocks 0..8191) and Wq/Wk/Wv (blocks 8192..11263).
__global__ void cvt_all(const float* __restrict__ x,
                        const float* __restrict__ Wq, const float* __restrict__ Wk,
                        const float* __restrict__ Wv,
                        uint16_t* __restrict__ x_bf, uint16_t* __restrict__ w_bf) {
    const int b = blockIdx.x;
    const float* src;
    uint16_t* dst;
    int i;
    if (b < 8192) {
        src = x; dst = x_bf; i = b * 256 + threadIdx.x;
    } else {
        const int wz = (b - 8192) >> 10;
        const int rb = (b - 8192) & 1023;
        src = (wz == 0) ? Wq : (wz == 1) ? Wk : Wv;
        dst = w_bf + (long long)wz * 1048576;
        i = rb * 256 + threadIdx.x;
    }
    const float4 f = ((const float4*)src)[i];
    ushort4 o;
    o.x = f2bf(f.x); o.y = f2bf(f.y); o.z = f2bf(f.z); o.w = f2bf(f.w);
    ((ushort4*)dst)[i] = o;
}

extern "C" void kernel_launch(void* const* d_in, const int* in_sizes, int n_in,
                              void* d_out, int out_size, void* d_ws, size_t ws_size,
                              hipStream_t stream) {
    const float* x  = (const float*)d_in[0];
    const float* Wq = (const float*)d_in[1];
    const float* bq = (const float*)d_in[2];
    const float* Wk = (const float*)d_in[3];
    const float* bk = (const float*)d_in[4];
    const float* Wv = (const float*)d_in[5];
    const float* bv = (const float*)d_in[6];
    float* out = (float*)d_out;

    char* w = (char*)d_ws;
    uint16_t* x_bf = (uint16_t*)(w);
    float*    gsum = (float*)(w);                 // overlays dead x_bf
    uint16_t* w_bf = (uint16_t*)(w + 16777216);
    uint8_t*  Qf8  = (uint8_t*)(w + 23068672);
    uint8_t*  Kf8  = (uint8_t*)(w + 31457280);
    uint16_t* Vt   = (uint16_t*)(w + 39845888);
    uint16_t* Pb   = (uint16_t*)(w + 56623104);

    // 1) fp32 -> bf16 conversions (x + all three W)
    cvt_all<<<11264, 256, 0, stream>>>(x, Wq, Wk, Wv, x_bf, w_bf);

    // 2) Q,K = x @ W^T + b  [8192,1024] fp8 out.  256x128: (32,8,2)=512 wg
    gemm2p<1, uint8_t><<<dim3(32, 8, 2), 512, 0, stream>>>(
        x_bf, 1024, 0LL,
        w_bf, 1024, 1048576LL,
        Qf8, 1024, 8388608LL,
        bq, bk, nullptr, 1024);

    // 2b) Vt[e, b*2048+s] = Wv x^T + bv  [1024,8192].  256x128: (4,64,1)=256 wg
    gemm2p<2, uint16_t><<<dim3(4, 64, 1), 512, 0, stream>>>(
        w_bf + 2097152, 1024, 0LL,
        x_bf, 1024, 0LL,
        Vt, 8192, 0LL,
        bv, bv, nullptr, 1024);

    // 3) P~_b = exp((Q_b K_b^T)/32) via MX-fp8 K=128; alpha = (1/32)*log2(e)
    score_f8<<<dim3(16, 16, 4), 256, 0, stream>>>(
        Qf8, Kf8, Pb, gsum, 0.045084222f);

    // 4) O_b = (P~_b @ V_b) / denom : fp32 out.  256x128: (8,8,4)=256 wg
    gemm2p<4, float><<<dim3(8, 8, 4), 512, 0, stream>>>(
        Pb, 2048, 4194304LL,
        Vt, 8192, 2048LL,
        out, 1024, 2097152LL,
        nullptr, nullptr, gsum, 2048);
}

// Round 5
// 229.688 us; speedup vs baseline: 1.1346x; 1.0922x over previous
//
#include <hip/hip_runtime.h>
#include <cstdint>

// B=4, S=2048, D=1024.  M_qkv = B*S = 8192.
// ws layout (bytes):
//   x_bf  @ 0        : 16,777,216  bf16 [8192][1024] (dead after Vt-proj;
//                      gsum f32[8192][16] overlays @0, written by score)
//   w_bf  @ 16777216 :  6,291,456  bf16 Wq,Wk,Wv each [1024][1024]
//   Qf8   @ 23068672 :  8,388,608  fp8 e4m3 [8192][1024]
//   Kf8   @ 31457280 :  8,388,608  fp8 e4m3 [8192][1024]
//   Vt    @ 39845888 : 16,777,216  bf16 [1024][8192], col = b*2048+s
//   P~    @ 56623104 : 33,554,432  bf16 [4][2048][2048] = exp(s/32), unnorm.

typedef __bf16 bf16x8_t __attribute__((ext_vector_type(8)));
typedef float  f32x4_t  __attribute__((ext_vector_type(4)));
typedef int    i32x8_t  __attribute__((ext_vector_type(8)));
typedef int    i32x4_t  __attribute__((ext_vector_type(4)));

__device__ __forceinline__ uint16_t f2bf(float f) {
    union { float f; uint32_t u; } v; v.f = f;
    return (uint16_t)((v.u + 0x7fffu + ((v.u >> 16) & 1u)) >> 16);  // RNE
}

// fp32 -> OCP e4m3fn, RNE.  Values here are |f| <~ 8, well inside range.
__device__ __forceinline__ uint8_t f2fp8(float f) {
    union { float f; uint32_t u; } v; v.f = f;
    const uint32_t sgn = (v.u >> 31) << 7;
    const uint32_t mag = v.u & 0x7fffffffu;
    uint32_t out;
    if (mag < 0x3c800000u) {                       // |f| < 2^-6: subnormal
        out = (uint32_t)__builtin_rintf(__builtin_fabsf(f) * 512.0f); // 0..8
    } else {
        uint32_t t = mag + 0x7ffffu + ((mag >> 20) & 1u);  // RNE at bit 20
        out = (t >> 20) - 960u;                            // (E<<3|m) - (120<<3)
        if (out > 0x7eu) out = 0x7eu;                      // clamp to 448
    }
    return (uint8_t)(sgn | out);
}

__device__ __forceinline__ void gload_lds16(const void* g, void* lds) {
    __builtin_amdgcn_global_load_lds(
        (const __attribute__((address_space(1))) void*)g,
        (__attribute__((address_space(3))) void*)lds, 16, 0, 0);
}

// ---------------------------------------------------------------------------
// bf16 B^T GEMM, 128x128 tile, templated BK (r5-proven structure at BK=64).
// R4 post-mortem: the R0/r5 structure (4 waves, 64x64 per-wave out, plain
// __syncthreads, 33KB LDS) measured 775 TF vs the 2-phase rewrite's 655 TF
// -- restored verbatim.  BK=128 variant for the GRID-LIMITED instances
// (PV: 512 wg, Vt: 512 wg -> both pinned at 2 blocks/CU regardless of LDS),
// where doubling BK halves the per-K-tile barrier+vmcnt(0)-drain count at
// zero occupancy cost (m132's BK=128 regression was occupancy-driven, 3->2;
// here occupancy is grid-capped at 2 either way).  QK (1024 wg, 4/CU at
// 33KB) stays BK=64.
//
// Swizzle (generalized from r5): staging slot s covers row r = s/CH,
// chunk (s%CH)^(r&(CH-1)) (CH = BK/8 16B-chunks per row); frag read XORs
// the same key: csw = ((t*4+quad)^(l15&(CH-1)))*8.  Per-16-lane bank-group
// multiplicity is 2 (free) for both CH=8 and CH=16; staging stays 1KB/wave
// contiguous (permutation within each row's 64/256B).
//
// EPI: 1 = +bias[n], fp8 out (Q/K proj -> fp8 score inputs)
//      2 = +bias[m], bf16 out (Vt proj)
//      4 = acc * (1/sum16(gsum_row)) fp32 out (PV)
// ---------------------------------------------------------------------------
template <int BK, int EPI, typename OutT>
__global__ __launch_bounds__(256, (BK == 64) ? 4 : 2) void gemm_bt(
    const uint16_t* __restrict__ A, int lda, long long sAz,
    const uint16_t* __restrict__ B, int ldb, long long sBz,
    OutT* __restrict__ C, int ldc, long long sCz,
    const float* __restrict__ bias0, const float* __restrict__ bias1,
    float* __restrict__ gsum, int K, float alpha)
{
    constexpr int CH = BK / 8;     // 16B chunks per row (8 or 16)
    constexpr int NC = BK / 16;    // staging gloads per matrix per thread

    __shared__ uint16_t ldsA[128 * BK];
    __shared__ uint16_t ldsB[128 * BK];
    __shared__ float inv_denom[128];

    const int tid  = threadIdx.x;
    const int wave = tid >> 6;
    const int lane = tid & 63;
    const int quad = lane >> 4;
    const int l15  = lane & 15;
    const int z    = blockIdx.z;

    A += (long long)z * sAz;
    B += (long long)z * sBz;
    C += (long long)z * sCz;

    const int m0 = blockIdx.x * 128;
    const int n0 = blockIdx.y * 128;

    if (EPI == 4) {
        if (tid < 128) {
            const float* gp = gsum + (long long)z * 32768 + (m0 + tid) * 16;
            float s = 0.f;
#pragma unroll
            for (int t = 0; t < 16; ++t) s += gp[t];
            inv_denom[tid] = 1.f / s;
        }
        // visibility via the K-loop's first __syncthreads
    }

    const uint16_t* gA[NC];
    const uint16_t* gB[NC];
    uint16_t* lA[NC];
    uint16_t* lB[NC];
#pragma unroll
    for (int c = 0; c < NC; ++c) {
        const int s   = (c * 4 + wave) * 64 + lane;
        const int r   = s / CH;
        const int col = ((s & (CH - 1)) ^ (r & (CH - 1))) * 8;
        gA[c] = A + (long long)(m0 + r) * lda + col;
        gB[c] = B + (long long)(n0 + r) * ldb + col;
        lA[c] = ldsA + (c * 4 + wave) * 512;   // wave-uniform base
        lB[c] = ldsB + (c * 4 + wave) * 512;
    }

    const int m_off = (wave & 1) * 64;
    const int n_off = (wave >> 1) * 64;

    f32x4_t acc[4][4];
#pragma unroll
    for (int i = 0; i < 4; ++i)
#pragma unroll
        for (int j = 0; j < 4; ++j)
            acc[i][j] = f32x4_t{0.f, 0.f, 0.f, 0.f};

    for (int k0 = 0; k0 < K; k0 += BK) {
#pragma unroll
        for (int c = 0; c < NC; ++c) gload_lds16(gA[c], lA[c]);
#pragma unroll
        for (int c = 0; c < NC; ++c) gload_lds16(gB[c], lB[c]);
#pragma unroll
        for (int c = 0; c < NC; ++c) { gA[c] += BK; gB[c] += BK; }
        __syncthreads();

#pragma unroll
        for (int t = 0; t < BK / 32; ++t) {
            const int csw = ((t * 4 + quad) ^ (l15 & (CH - 1))) * 8;
            bf16x8_t af[4], bfr[4];
#pragma unroll
            for (int i = 0; i < 4; ++i)
                af[i] = *(const bf16x8_t*)(ldsA + (m_off + i * 16 + l15) * BK + csw);
#pragma unroll
            for (int j = 0; j < 4; ++j)
                bfr[j] = *(const bf16x8_t*)(ldsB + (n_off + j * 16 + l15) * BK + csw);
#pragma unroll
            for (int i = 0; i < 4; ++i)
#pragma unroll
                for (int j = 0; j < 4; ++j)
                    acc[i][j] = __builtin_amdgcn_mfma_f32_16x16x32_bf16(af[i], bfr[j], acc[i][j], 0, 0, 0);
        }
        __syncthreads();
    }

    if (EPI == 1 || EPI == 2) {
        const float* bias = (z == 0) ? bias0 : bias1;
#pragma unroll
        for (int i = 0; i < 4; ++i) {
            const int mb = m0 + m_off + i * 16 + quad * 4;
            float rb[4];
            if (EPI == 2) {
#pragma unroll
                for (int r = 0; r < 4; ++r) rb[r] = bias[mb + r];
            }
#pragma unroll
            for (int j = 0; j < 4; ++j) {
                const int n = n0 + n_off + j * 16 + l15;
                const float cb = (EPI == 1) ? bias[n] : 0.f;
#pragma unroll
                for (int r = 0; r < 4; ++r) {
                    const float v = acc[i][j][r] + ((EPI == 1) ? cb : rb[r]);
                    if (sizeof(OutT) == 1)
                        ((uint8_t*)C)[(long long)(mb + r) * ldc + n] = f2fp8(v);
                    else
                        ((uint16_t*)C)[(long long)(mb + r) * ldc + n] = f2bf(v);
                }
            }
        }
    } else {  // EPI == 4
#pragma unroll
        for (int i = 0; i < 4; ++i) {
            const int rl = m_off + i * 16 + quad * 4;
            const int mb = m0 + rl;
#pragma unroll
            for (int j = 0; j < 4; ++j) {
                const int n = n0 + n_off + j * 16 + l15;
#pragma unroll
                for (int r = 0; r < 4; ++r)
                    ((float*)C)[(long long)(mb + r) * ldc + n] =
                        acc[i][j][r] * inv_denom[rl + r];
            }
        }
    }
}

// ---------------------------------------------------------------------------
// fp8 score GEMM: P~ = exp((Q K^T)/32), MX-fp8 MFMA K=128 with unit scales.
// Tile 128x128, BK=128 fp8 (128 B/row — byte-identical LDS layout + XOR
// swizzle as the bf16 kernel).  C/D layout is shape-determined (16x16), so
// the EPI-3 epilogue is the r5-verified code verbatim.
// ---------------------------------------------------------------------------
__global__ __launch_bounds__(256, 3) void score_f8(
    const uint8_t* __restrict__ Qf8, const uint8_t* __restrict__ Kf8,
    uint16_t* __restrict__ P, float* __restrict__ gsum, float alpha)
{
    __shared__ uint8_t ldsA[128 * 128];
    __shared__ uint8_t ldsB[128 * 128];

    const int tid  = threadIdx.x;
    const int wave = tid >> 6;
    const int lane = tid & 63;
    const int quad = lane >> 4;
    const int l15  = lane & 15;
    const int z    = blockIdx.z;

    const uint8_t* A = Qf8 + (long long)z * 2097152;
    const uint8_t* B = Kf8 + (long long)z * 2097152;
    uint16_t* C = P + (long long)z * 4194304;

    const int m0 = blockIdx.x * 128;
    const int n0 = blockIdx.y * 128;

    // staging: 1024 16B slots/side; slot s -> row r=s>>3, holds global chunk
    // (s&7)^(r&7) (16 fp8 k's per chunk, 8 chunks = 128 k per row).
    const uint8_t* gA[4];
    const uint8_t* gB[4];
    uint8_t* lA[4];
    uint8_t* lB[4];
#pragma unroll
    for (int c = 0; c < 4; ++c) {
        const int s   = (c * 4 + wave) * 64 + lane;
        const int r   = s >> 3;
        const int col = ((s & 7) ^ (r & 7)) * 16;
        gA[c] = A + (long long)(m0 + r) * 1024 + col;
        gB[c] = B + (long long)(n0 + r) * 1024 + col;
        lA[c] = ldsA + (c * 4 + wave) * 1024;   // wave-uniform base
        lB[c] = ldsB + (c * 4 + wave) * 1024;
    }

    const int m_off = (wave & 1) * 64;
    const int n_off = (wave >> 1) * 64;

    f32x4_t acc[4][4];
#pragma unroll
    for (int i = 0; i < 4; ++i)
#pragma unroll
        for (int j = 0; j < 4; ++j)
            acc[i][j] = f32x4_t{0.f, 0.f, 0.f, 0.f};

    // frag k = quad*32 + j (j 0..31): global chunks 2q (k 32q..+15) and
    // 2q+1 (k 32q+16..+31), swizzle-relocated independently.
    const int h0 = quad * 2;
    const int h1 = quad * 2 + 1;

    for (int k0 = 0; k0 < 1024; k0 += 128) {
#pragma unroll
        for (int c = 0; c < 4; ++c) gload_lds16(gA[c], lA[c]);
#pragma unroll
        for (int c = 0; c < 4; ++c) gload_lds16(gB[c], lB[c]);
#pragma unroll
        for (int c = 0; c < 4; ++c) { gA[c] += 128; gB[c] += 128; }
        __syncthreads();

        i32x8_t af[4], bfr[4];
#pragma unroll
        for (int i = 0; i < 4; ++i) {
            const int m = m_off + i * 16 + l15;
            const int sw = m & 7;
            const i32x4_t lo = *(const i32x4_t*)(ldsA + m * 128 + (h0 ^ sw) * 16);
            const i32x4_t hi = *(const i32x4_t*)(ldsA + m * 128 + (h1 ^ sw) * 16);
            af[i] = i32x8_t{lo[0], lo[1], lo[2], lo[3], hi[0], hi[1], hi[2], hi[3]};
        }
#pragma unroll
        for (int j = 0; j < 4; ++j) {
            const int n = n_off + j * 16 + l15;
            const int sw = n & 7;
            const i32x4_t lo = *(const i32x4_t*)(ldsB + n * 128 + (h0 ^ sw) * 16);
            const i32x4_t hi = *(const i32x4_t*)(ldsB + n * 128 + (h1 ^ sw) * 16);
            bfr[j] = i32x8_t{lo[0], lo[1], lo[2], lo[3], hi[0], hi[1], hi[2], hi[3]};
        }
#pragma unroll
        for (int i = 0; i < 4; ++i)
#pragma unroll
            for (int j = 0; j < 4; ++j)
                acc[i][j] = __builtin_amdgcn_mfma_scale_f32_16x16x128_f8f6f4(
                    af[i], bfr[j], acc[i][j],
                    0, 0,                       // cbsz, blgp: fp8 e4m3 / fp8 e4m3
                    0, 0x7f7f7f7f,              // opsel_a, scale_a (e8m0 127 = x1)
                    0, 0x7f7f7f7f);             // opsel_b, scale_b
        __syncthreads();
    }

    // EPI-3 epilogue (r5-verified, C/D layout shape-determined).
    float rs[4][4];
#pragma unroll
    for (int i = 0; i < 4; ++i)
#pragma unroll
        for (int r = 0; r < 4; ++r) rs[i][r] = 0.f;
#pragma unroll
    for (int i = 0; i < 4; ++i) {
        const int mb = m0 + m_off + i * 16 + quad * 4;
#pragma unroll
        for (int j = 0; j < 4; ++j) {
            const int n = n0 + n_off + j * 16 + l15;
#pragma unroll
            for (int r = 0; r < 4; ++r) {
                const float e = exp2f(acc[i][j][r] * alpha);
                rs[i][r] += e;
                C[(long long)(mb + r) * 2048 + n] = f2bf(e);
            }
        }
    }
#pragma unroll
    for (int m = 1; m < 16; m <<= 1)
#pragma unroll
        for (int i = 0; i < 4; ++i)
#pragma unroll
            for (int r = 0; r < 4; ++r)
                rs[i][r] += __shfl_xor(rs[i][r], m);
    float* lp = (float*)ldsA;   // reuse past last barrier: [4 waves][64 rows]
    if (l15 == 0) {
#pragma unroll
        for (int i = 0; i < 4; ++i)
#pragma unroll
            for (int r = 0; r < 4; ++r)
                lp[wave * 64 + i * 16 + quad * 4 + r] = rs[i][r];
    }
    __syncthreads();
    if (tid < 128) {
        const float s = lp[(tid >> 6) * 64 + (tid & 63)] +
                        lp[((tid >> 6) + 2) * 64 + (tid & 63)];
        gsum[(long long)z * 32768 + (m0 + tid) * 16 + blockIdx.y] = s;
    }
}

// fp32 -> bf16 for x (blocks 0..8191) and Wq/Wk/Wv (blocks 8192..11263).
__global__ void cvt_all(const float* __restrict__ x,
                        const float* __restrict__ Wq, const float* __restrict__ Wk,
                        const float* __restrict__ Wv,
                        uint16_t* __restrict__ x_bf, uint16_t* __restrict__ w_bf) {
    const int b = blockIdx.x;
    const float* src;
    uint16_t* dst;
    int i;
    if (b < 8192) {
        src = x; dst = x_bf; i = b * 256 + threadIdx.x;
    } else {
        const int wz = (b - 8192) >> 10;
        const int rb = (b - 8192) & 1023;
        src = (wz == 0) ? Wq : (wz == 1) ? Wk : Wv;
        dst = w_bf + (long long)wz * 1048576;
        i = rb * 256 + threadIdx.x;
    }
    const float4 f = ((const float4*)src)[i];
    ushort4 o;
    o.x = f2bf(f.x); o.y = f2bf(f.y); o.z = f2bf(f.z); o.w = f2bf(f.w);
    ((ushort4*)dst)[i] = o;
}

extern "C" void kernel_launch(void* const* d_in, const int* in_sizes, int n_in,
                              void* d_out, int out_size, void* d_ws, size_t ws_size,
                              hipStream_t stream) {
    const float* x  = (const float*)d_in[0];
    const float* Wq = (const float*)d_in[1];
    const float* bq = (const float*)d_in[2];
    const float* Wk = (const float*)d_in[3];
    const float* bk = (const float*)d_in[4];
    const float* Wv = (const float*)d_in[5];
    const float* bv = (const float*)d_in[6];
    float* out = (float*)d_out;

    char* w = (char*)d_ws;
    uint16_t* x_bf = (uint16_t*)(w);
    float*    gsum = (float*)(w);                 // overlays dead x_bf
    uint16_t* w_bf = (uint16_t*)(w + 16777216);
    uint8_t*  Qf8  = (uint8_t*)(w + 23068672);
    uint8_t*  Kf8  = (uint8_t*)(w + 31457280);
    uint16_t* Vt   = (uint16_t*)(w + 39845888);
    uint16_t* Pb   = (uint16_t*)(w + 56623104);

    // 1) fp32 -> bf16 conversions (x + all three W)
    cvt_all<<<11264, 256, 0, stream>>>(x, Wq, Wk, Wv, x_bf, w_bf);

    // 2) Q,K = x @ W^T + b   [8192,1024] fp8 out.  BK=64, 1024 wg (4/CU)
    gemm_bt<64, 1, uint8_t><<<dim3(64, 8, 2), 256, 0, stream>>>(
        x_bf, 1024, 0LL,
        w_bf, 1024, 1048576LL,
        Qf8, 1024, 8388608LL,
        bq, bk, nullptr, 1024, 1.0f);

    // 2b) Vt[e, b*2048+s] = Wv x^T + bv  [1024,8192].  BK=128 (grid-limited
    //     512 wg = 2/CU either way -> halved barrier count is free)
    gemm_bt<128, 2, uint16_t><<<dim3(8, 64, 1), 256, 0, stream>>>(
        w_bf + 2097152, 1024, 0LL,
        x_bf, 1024, 0LL,
        Vt, 8192, 0LL,
        bv, bv, nullptr, 1024, 1.0f);

    // 3) P~_b = exp((Q_b K_b^T)/32) via MX-fp8 K=128; alpha = (1/32)*log2(e)
    score_f8<<<dim3(16, 16, 4), 256, 0, stream>>>(
        Qf8, Kf8, Pb, gsum, 0.045084222f);

    // 4) O_b = (P~_b @ V_b) / denom : fp32 out.  BK=128 (grid-limited 512 wg)
    gemm_bt<128, 4, float><<<dim3(16, 8, 4), 256, 0, stream>>>(
        Pb, 2048, 4194304LL,
        Vt, 8192, 2048LL,
        out, 1024, 2097152LL,
        nullptr, nullptr, gsum, 2048, 1.0f);
}

// Round 6
// 226.426 us; speedup vs baseline: 1.1509x; 1.0144x over previous
//
#include <hip/hip_runtime.h>
#include <cstdint>

// B=4, S=2048, D=1024.  M_qkv = B*S = 8192.
// ws layout (bytes):
//   x_bf  @ 0        : 16,777,216  bf16 [8192][1024] (dead after Vt-proj;
//                      gsum f32[8192][16] overlays @0, written by score)
//   w_bf  @ 16777216 :  6,291,456  bf16 Wq,Wk,Wv each [1024][1024]
//   Qf8   @ 23068672 :  8,388,608  fp8 e4m3 [8192][1024]
//   Kf8   @ 31457280 :  8,388,608  fp8 e4m3 [8192][1024]
//   Vt    @ 39845888 : 16,777,216  bf16 [1024][8192], col = b*2048+s
//   P~    @ 56623104 : 33,554,432  bf16 [4][2048][2048] = exp(s/32), unnorm.

typedef __bf16 bf16x8_t __attribute__((ext_vector_type(8)));
typedef float  f32x4_t  __attribute__((ext_vector_type(4)));
typedef int    i32x8_t  __attribute__((ext_vector_type(8)));
typedef int    i32x4_t  __attribute__((ext_vector_type(4)));

__device__ __forceinline__ uint16_t f2bf(float f) {
    union { float f; uint32_t u; } v; v.f = f;
    return (uint16_t)((v.u + 0x7fffu + ((v.u >> 16) & 1u)) >> 16);  // RNE
}

// fp32 -> OCP e4m3fn, RNE.  Values here are |f| <~ 8, well inside range.
__device__ __forceinline__ uint8_t f2fp8(float f) {
    union { float f; uint32_t u; } v; v.f = f;
    const uint32_t sgn = (v.u >> 31) << 7;
    const uint32_t mag = v.u & 0x7fffffffu;
    uint32_t out;
    if (mag < 0x3c800000u) {                       // |f| < 2^-6: subnormal
        out = (uint32_t)__builtin_rintf(__builtin_fabsf(f) * 512.0f); // 0..8
    } else {
        uint32_t t = mag + 0x7ffffu + ((mag >> 20) & 1u);  // RNE at bit 20
        out = (t >> 20) - 960u;                            // (E<<3|m) - (120<<3)
        if (out > 0x7eu) out = 0x7eu;                      // clamp to 448
    }
    return (uint8_t)(sgn | out);
}

__device__ __forceinline__ void gload_lds16(const void* g, void* lds) {
    __builtin_amdgcn_global_load_lds(
        (const __attribute__((address_space(1))) void*)g,
        (__attribute__((address_space(3))) void*)lds, 16, 0, 0);
}

// ---------------------------------------------------------------------------
// bf16 B^T GEMM, 128x128 tile, templated BK (r5-proven structure at BK=64;
// R5: BK=128 for the grid-limited instances, PV 44.4->41.7us).
//
// R6: T1 XCD-chunked block swizzle.  HW dispatch round-robins blocks over
// the 8 XCDs (private, non-coherent L2s); blocks sharing an operand panel
// land on different L2s and re-fetch from HBM (PV FETCH 82MB vs ~48MB
// unique).  Bijective remap (nwg%8==0 for every per-z grid here) gives each
// XCD a contiguous band of work; MAJX picks which tile axis the band runs
// along so same-XCD blocks share the LARGER operand:
//   MAJX=1: band of bx (share A panel)  -- QK (A=x 16MB), PV (A=P 8MB/z)
//   MAJX=0: band of by (share B panel)  -- Vt (B=x 16MB)
// Pure index permutation: zero correctness risk.
//
// Swizzle (r5): staging slot s covers row r = s/CH, chunk
// (s%CH)^(r&(CH-1)) (CH = BK/8 16B-chunks per row); frag read XORs the same
// key: csw = ((t*4+quad)^(l15&(CH-1)))*8.  Conflict-free (measured 0).
//
// EPI: 1 = +bias[n], fp8 out (Q/K proj -> fp8 score inputs)
//      2 = +bias[m], bf16 out (Vt proj)
//      4 = acc * (1/sum16(gsum_row)) fp32 out (PV)
// ---------------------------------------------------------------------------
template <int BK, int EPI, int MAJX, typename OutT>
__global__ __launch_bounds__(256, (BK == 64) ? 4 : 2) void gemm_bt(
    const uint16_t* __restrict__ A, int lda, long long sAz,
    const uint16_t* __restrict__ B, int ldb, long long sBz,
    OutT* __restrict__ C, int ldc, long long sCz,
    const float* __restrict__ bias0, const float* __restrict__ bias1,
    float* __restrict__ gsum, int K, float alpha)
{
    constexpr int CH = BK / 8;     // 16B chunks per row (8 or 16)
    constexpr int NC = BK / 16;    // staging gloads per matrix per thread

    __shared__ uint16_t ldsA[128 * BK];
    __shared__ uint16_t ldsB[128 * BK];
    __shared__ float inv_denom[128];

    const int tid  = threadIdx.x;
    const int wave = tid >> 6;
    const int lane = tid & 63;
    const int quad = lane >> 4;
    const int l15  = lane & 15;
    const int z    = blockIdx.z;

    A += (long long)z * sAz;
    B += (long long)z * sBz;
    C += (long long)z * sCz;

    // ---- T1 XCD-chunked remap (per z-slice; nwg%8==0 at all call sites)
    int bx, by;
    {
        const int gx  = gridDim.x, gy = gridDim.y;
        const int nwg = gx * gy;
        int f = blockIdx.y * gx + blockIdx.x;      // hw dispatch order (x fastest)
        f = (f & 7) * (nwg >> 3) + (f >> 3);       // XCD k -> contiguous work band
        if (MAJX) { bx = f / gy; by = f % gy; }    // band runs along bx
        else      { by = f / gx; bx = f % gx; }    // band runs along by
    }
    const int m0 = bx * 128;
    const int n0 = by * 128;

    if (EPI == 4) {
        if (tid < 128) {
            const float* gp = gsum + (long long)z * 32768 + (m0 + tid) * 16;
            float s = 0.f;
#pragma unroll
            for (int t = 0; t < 16; ++t) s += gp[t];
            inv_denom[tid] = 1.f / s;
        }
        // visibility via the K-loop's first __syncthreads
    }

    const uint16_t* gA[NC];
    const uint16_t* gB[NC];
    uint16_t* lA[NC];
    uint16_t* lB[NC];
#pragma unroll
    for (int c = 0; c < NC; ++c) {
        const int s   = (c * 4 + wave) * 64 + lane;
        const int r   = s / CH;
        const int col = ((s & (CH - 1)) ^ (r & (CH - 1))) * 8;
        gA[c] = A + (long long)(m0 + r) * lda + col;
        gB[c] = B + (long long)(n0 + r) * ldb + col;
        lA[c] = ldsA + (c * 4 + wave) * 512;   // wave-uniform base
        lB[c] = ldsB + (c * 4 + wave) * 512;
    }

    const int m_off = (wave & 1) * 64;
    const int n_off = (wave >> 1) * 64;

    f32x4_t acc[4][4];
#pragma unroll
    for (int i = 0; i < 4; ++i)
#pragma unroll
        for (int j = 0; j < 4; ++j)
            acc[i][j] = f32x4_t{0.f, 0.f, 0.f, 0.f};

    for (int k0 = 0; k0 < K; k0 += BK) {
#pragma unroll
        for (int c = 0; c < NC; ++c) gload_lds16(gA[c], lA[c]);
#pragma unroll
        for (int c = 0; c < NC; ++c) gload_lds16(gB[c], lB[c]);
#pragma unroll
        for (int c = 0; c < NC; ++c) { gA[c] += BK; gB[c] += BK; }
        __syncthreads();

#pragma unroll
        for (int t = 0; t < BK / 32; ++t) {
            const int csw = ((t * 4 + quad) ^ (l15 & (CH - 1))) * 8;
            bf16x8_t af[4], bfr[4];
#pragma unroll
            for (int i = 0; i < 4; ++i)
                af[i] = *(const bf16x8_t*)(ldsA + (m_off + i * 16 + l15) * BK + csw);
#pragma unroll
            for (int j = 0; j < 4; ++j)
                bfr[j] = *(const bf16x8_t*)(ldsB + (n_off + j * 16 + l15) * BK + csw);
#pragma unroll
            for (int i = 0; i < 4; ++i)
#pragma unroll
                for (int j = 0; j < 4; ++j)
                    acc[i][j] = __builtin_amdgcn_mfma_f32_16x16x32_bf16(af[i], bfr[j], acc[i][j], 0, 0, 0);
        }
        __syncthreads();
    }

    if (EPI == 1 || EPI == 2) {
        const float* bias = (z == 0) ? bias0 : bias1;
#pragma unroll
        for (int i = 0; i < 4; ++i) {
            const int mb = m0 + m_off + i * 16 + quad * 4;
            float rb[4];
            if (EPI == 2) {
#pragma unroll
                for (int r = 0; r < 4; ++r) rb[r] = bias[mb + r];
            }
#pragma unroll
            for (int j = 0; j < 4; ++j) {
                const int n = n0 + n_off + j * 16 + l15;
                const float cb = (EPI == 1) ? bias[n] : 0.f;
#pragma unroll
                for (int r = 0; r < 4; ++r) {
                    const float v = acc[i][j][r] + ((EPI == 1) ? cb : rb[r]);
                    if (sizeof(OutT) == 1)
                        ((uint8_t*)C)[(long long)(mb + r) * ldc + n] = f2fp8(v);
                    else
                        ((uint16_t*)C)[(long long)(mb + r) * ldc + n] = f2bf(v);
                }
            }
        }
    } else {  // EPI == 4
#pragma unroll
        for (int i = 0; i < 4; ++i) {
            const int rl = m_off + i * 16 + quad * 4;
            const int mb = m0 + rl;
#pragma unroll
            for (int j = 0; j < 4; ++j) {
                const int n = n0 + n_off + j * 16 + l15;
#pragma unroll
                for (int r = 0; r < 4; ++r)
                    ((float*)C)[(long long)(mb + r) * ldc + n] =
                        acc[i][j][r] * inv_denom[rl + r];
            }
        }
    }
}

// ---------------------------------------------------------------------------
// fp8 score GEMM: P~ = exp((Q K^T)/32), MX-fp8 MFMA K=128 with unit scales.
// Tile 128x128, BK=128 fp8.  R6: + XCD-chunked swizzle (bx-major; Q/K both
// 2MB/z so either axis L2-fits — bx keeps the gsum slot = by mapping 1:1).
// ---------------------------------------------------------------------------
__global__ __launch_bounds__(256, 3) void score_f8(
    const uint8_t* __restrict__ Qf8, const uint8_t* __restrict__ Kf8,
    uint16_t* __restrict__ P, float* __restrict__ gsum, float alpha)
{
    __shared__ uint8_t ldsA[128 * 128];
    __shared__ uint8_t ldsB[128 * 128];

    const int tid  = threadIdx.x;
    const int wave = tid >> 6;
    const int lane = tid & 63;
    const int quad = lane >> 4;
    const int l15  = lane & 15;
    const int z    = blockIdx.z;

    const uint8_t* A = Qf8 + (long long)z * 2097152;
    const uint8_t* B = Kf8 + (long long)z * 2097152;
    uint16_t* C = P + (long long)z * 4194304;

    // ---- T1 XCD-chunked remap (nwg = 256 per z)
    int bx, by;
    {
        const int gx  = gridDim.x, gy = gridDim.y;
        const int nwg = gx * gy;
        int f = blockIdx.y * gx + blockIdx.x;
        f = (f & 7) * (nwg >> 3) + (f >> 3);
        bx = f / gy; by = f % gy;
    }
    const int m0 = bx * 128;
    const int n0 = by * 128;

    // staging: 1024 16B slots/side; slot s -> row r=s>>3, holds global chunk
    // (s&7)^(r&7) (16 fp8 k's per chunk, 8 chunks = 128 k per row).
    const uint8_t* gA[4];
    const uint8_t* gB[4];
    uint8_t* lA[4];
    uint8_t* lB[4];
#pragma unroll
    for (int c = 0; c < 4; ++c) {
        const int s   = (c * 4 + wave) * 64 + lane;
        const int r   = s >> 3;
        const int col = ((s & 7) ^ (r & 7)) * 16;
        gA[c] = A + (long long)(m0 + r) * 1024 + col;
        gB[c] = B + (long long)(n0 + r) * 1024 + col;
        lA[c] = ldsA + (c * 4 + wave) * 1024;   // wave-uniform base
        lB[c] = ldsB + (c * 4 + wave) * 1024;
    }

    const int m_off = (wave & 1) * 64;
    const int n_off = (wave >> 1) * 64;

    f32x4_t acc[4][4];
#pragma unroll
    for (int i = 0; i < 4; ++i)
#pragma unroll
        for (int j = 0; j < 4; ++j)
            acc[i][j] = f32x4_t{0.f, 0.f, 0.f, 0.f};

    // frag k = quad*32 + j (j 0..31): global chunks 2q (k 32q..+15) and
    // 2q+1 (k 32q+16..+31), swizzle-relocated independently.
    const int h0 = quad * 2;
    const int h1 = quad * 2 + 1;

    for (int k0 = 0; k0 < 1024; k0 += 128) {
#pragma unroll
        for (int c = 0; c < 4; ++c) gload_lds16(gA[c], lA[c]);
#pragma unroll
        for (int c = 0; c < 4; ++c) gload_lds16(gB[c], lB[c]);
#pragma unroll
        for (int c = 0; c < 4; ++c) { gA[c] += 128; gB[c] += 128; }
        __syncthreads();

        i32x8_t af[4], bfr[4];
#pragma unroll
        for (int i = 0; i < 4; ++i) {
            const int m = m_off + i * 16 + l15;
            const int sw = m & 7;
            const i32x4_t lo = *(const i32x4_t*)(ldsA + m * 128 + (h0 ^ sw) * 16);
            const i32x4_t hi = *(const i32x4_t*)(ldsA + m * 128 + (h1 ^ sw) * 16);
            af[i] = i32x8_t{lo[0], lo[1], lo[2], lo[3], hi[0], hi[1], hi[2], hi[3]};
        }
#pragma unroll
        for (int j = 0; j < 4; ++j) {
            const int n = n_off + j * 16 + l15;
            const int sw = n & 7;
            const i32x4_t lo = *(const i32x4_t*)(ldsB + n * 128 + (h0 ^ sw) * 16);
            const i32x4_t hi = *(const i32x4_t*)(ldsB + n * 128 + (h1 ^ sw) * 16);
            bfr[j] = i32x8_t{lo[0], lo[1], lo[2], lo[3], hi[0], hi[1], hi[2], hi[3]};
        }
#pragma unroll
        for (int i = 0; i < 4; ++i)
#pragma unroll
            for (int j = 0; j < 4; ++j)
                acc[i][j] = __builtin_amdgcn_mfma_scale_f32_16x16x128_f8f6f4(
                    af[i], bfr[j], acc[i][j],
                    0, 0,                       // cbsz, blgp: fp8 e4m3 / fp8 e4m3
                    0, 0x7f7f7f7f,              // opsel_a, scale_a (e8m0 127 = x1)
                    0, 0x7f7f7f7f);             // opsel_b, scale_b
        __syncthreads();
    }

    // EPI-3 epilogue (r5-verified, C/D layout shape-determined).
    float rs[4][4];
#pragma unroll
    for (int i = 0; i < 4; ++i)
#pragma unroll
        for (int r = 0; r < 4; ++r) rs[i][r] = 0.f;
#pragma unroll
    for (int i = 0; i < 4; ++i) {
        const int mb = m0 + m_off + i * 16 + quad * 4;
#pragma unroll
        for (int j = 0; j < 4; ++j) {
            const int n = n0 + n_off + j * 16 + l15;
#pragma unroll
            for (int r = 0; r < 4; ++r) {
                const float e = exp2f(acc[i][j][r] * alpha);
                rs[i][r] += e;
                C[(long long)(mb + r) * 2048 + n] = f2bf(e);
            }
        }
    }
#pragma unroll
    for (int m = 1; m < 16; m <<= 1)
#pragma unroll
        for (int i = 0; i < 4; ++i)
#pragma unroll
            for (int r = 0; r < 4; ++r)
                rs[i][r] += __shfl_xor(rs[i][r], m);
    float* lp = (float*)ldsA;   // reuse past last barrier: [4 waves][64 rows]
    if (l15 == 0) {
#pragma unroll
        for (int i = 0; i < 4; ++i)
#pragma unroll
            for (int r = 0; r < 4; ++r)
                lp[wave * 64 + i * 16 + quad * 4 + r] = rs[i][r];
    }
    __syncthreads();
    if (tid < 128) {
        const float s = lp[(tid >> 6) * 64 + (tid & 63)] +
                        lp[((tid >> 6) + 2) * 64 + (tid & 63)];
        gsum[(long long)z * 32768 + (m0 + tid) * 16 + by] = s;   // by = swizzled n-tile
    }
}

// fp32 -> bf16 for x (blocks 0..8191) and Wq/Wk/Wv (blocks 8192..11263).
__global__ void cvt_all(const float* __restrict__ x,
                        const float* __restrict__ Wq, const float* __restrict__ Wk,
                        const float* __restrict__ Wv,
                        uint16_t* __restrict__ x_bf, uint16_t* __restrict__ w_bf) {
    const int b = blockIdx.x;
    const float* src;
    uint16_t* dst;
    int i;
    if (b < 8192) {
        src = x; dst = x_bf; i = b * 256 + threadIdx.x;
    } else {
        const int wz = (b - 8192) >> 10;
        const int rb = (b - 8192) & 1023;
        src = (wz == 0) ? Wq : (wz == 1) ? Wk : Wv;
        dst = w_bf + (long long)wz * 1048576;
        i = rb * 256 + threadIdx.x;
    }
    const float4 f = ((const float4*)src)[i];
    ushort4 o;
    o.x = f2bf(f.x); o.y = f2bf(f.y); o.z = f2bf(f.z); o.w = f2bf(f.w);
    ((ushort4*)dst)[i] = o;
}

extern "C" void kernel_launch(void* const* d_in, const int* in_sizes, int n_in,
                              void* d_out, int out_size, void* d_ws, size_t ws_size,
                              hipStream_t stream) {
    const float* x  = (const float*)d_in[0];
    const float* Wq = (const float*)d_in[1];
    const float* bq = (const float*)d_in[2];
    const float* Wk = (const float*)d_in[3];
    const float* bk = (const float*)d_in[4];
    const float* Wv = (const float*)d_in[5];
    const float* bv = (const float*)d_in[6];
    float* out = (float*)d_out;

    char* w = (char*)d_ws;
    uint16_t* x_bf = (uint16_t*)(w);
    float*    gsum = (float*)(w);                 // overlays dead x_bf
    uint16_t* w_bf = (uint16_t*)(w + 16777216);
    uint8_t*  Qf8  = (uint8_t*)(w + 23068672);
    uint8_t*  Kf8  = (uint8_t*)(w + 31457280);
    uint16_t* Vt   = (uint16_t*)(w + 39845888);
    uint16_t* Pb   = (uint16_t*)(w + 56623104);

    // 1) fp32 -> bf16 conversions (x + all three W)
    cvt_all<<<11264, 256, 0, stream>>>(x, Wq, Wk, Wv, x_bf, w_bf);

    // 2) Q,K = x @ W^T + b   [8192,1024] fp8 out.  BK=64, 1024 wg (4/CU);
    //    MAJX=1: same-XCD blocks share the x A-panel (16 MB operand)
    gemm_bt<64, 1, 1, uint8_t><<<dim3(64, 8, 2), 256, 0, stream>>>(
        x_bf, 1024, 0LL,
        w_bf, 1024, 1048576LL,
        Qf8, 1024, 8388608LL,
        bq, bk, nullptr, 1024, 1.0f);

    // 2b) Vt[e, b*2048+s] = Wv x^T + bv  [1024,8192].  BK=128 (grid-limited);
    //     MAJX=0: same-XCD blocks share the x B-panel
    gemm_bt<128, 2, 0, uint16_t><<<dim3(8, 64, 1), 256, 0, stream>>>(
        w_bf + 2097152, 1024, 0LL,
        x_bf, 1024, 0LL,
        Vt, 8192, 0LL,
        bv, bv, nullptr, 1024, 1.0f);

    // 3) P~_b = exp((Q_b K_b^T)/32) via MX-fp8 K=128; alpha = (1/32)*log2(e)
    score_f8<<<dim3(16, 16, 4), 256, 0, stream>>>(
        Qf8, Kf8, Pb, gsum, 0.045084222f);

    // 4) O_b = (P~_b @ V_b) / denom : fp32 out.  BK=128 (grid-limited);
    //    MAJX=1: same-XCD blocks share the P A-panel (8 MB/z operand)
    gemm_bt<128, 4, 1, float><<<dim3(16, 8, 4), 256, 0, stream>>>(
        Pb, 2048, 4194304LL,
        Vt, 8192, 2048LL,
        out, 1024, 2097152LL,
        nullptr, nullptr, gsum, 2048, 1.0f);
}

// Round 8
// 226.327 us; speedup vs baseline: 1.1514x; 1.0004x over previous
//
#include <hip/hip_runtime.h>
#include <cstdint>

// B=4, S=2048, D=1024.  M_qkv = B*S = 8192.
// ws layout (bytes):
//   x_bf  @ 0        : 16,777,216  bf16 [8192][1024] (dead after Vt-proj;
//                      gsum f32[8192][16] overlays @0, written by score)
//   w_bf  @ 16777216 :  6,291,456  bf16 Wq,Wk,Wv each [1024][1024]
//   Qf8   @ 23068672 :  8,388,608  fp8 e4m3 [8192][1024]
//   Kf8   @ 31457280 :  8,388,608  fp8 e4m3 [8192][1024]
//   Vt    @ 39845888 : 16,777,216  bf16 [1024][8192], col = b*2048+s
//   P~    @ 56623104 : 33,554,432  bf16 [4][2048][2048] = exp(s/32), unnorm.
//
// R8 = R6 revert.  R7 (fp8 P and V for PV at 2x MFMA rate) failed accuracy:
// absmax 2.98e-3 > 1.92e-3 threshold; the PV-quant contribution alone was
// ~2.7e-3 (quadrature) and no fp8/int8 scheme cuts it the required 2x
// without doubling MFMA work.  bf16 PV is the accuracy floor.

typedef __bf16 bf16x8_t __attribute__((ext_vector_type(8)));
typedef float  f32x4_t  __attribute__((ext_vector_type(4)));
typedef int    i32x8_t  __attribute__((ext_vector_type(8)));
typedef int    i32x4_t  __attribute__((ext_vector_type(4)));

__device__ __forceinline__ uint16_t f2bf(float f) {
    union { float f; uint32_t u; } v; v.f = f;
    return (uint16_t)((v.u + 0x7fffu + ((v.u >> 16) & 1u)) >> 16);  // RNE
}

// fp32 -> OCP e4m3fn, RNE.  Values here are |f| <~ 8, well inside range.
__device__ __forceinline__ uint8_t f2fp8(float f) {
    union { float f; uint32_t u; } v; v.f = f;
    const uint32_t sgn = (v.u >> 31) << 7;
    const uint32_t mag = v.u & 0x7fffffffu;
    uint32_t out;
    if (mag < 0x3c800000u) {                       // |f| < 2^-6: subnormal
        out = (uint32_t)__builtin_rintf(__builtin_fabsf(f) * 512.0f); // 0..8
    } else {
        uint32_t t = mag + 0x7ffffu + ((mag >> 20) & 1u);  // RNE at bit 20
        out = (t >> 20) - 960u;                            // (E<<3|m) - (120<<3)
        if (out > 0x7eu) out = 0x7eu;                      // clamp to 448
    }
    return (uint8_t)(sgn | out);
}

__device__ __forceinline__ void gload_lds16(const void* g, void* lds) {
    __builtin_amdgcn_global_load_lds(
        (const __attribute__((address_space(1))) void*)g,
        (__attribute__((address_space(3))) void*)lds, 16, 0, 0);
}

// ---------------------------------------------------------------------------
// bf16 B^T GEMM, 128x128 tile, templated BK (r5-proven structure at BK=64;
// R5: BK=128 for the grid-limited instances, PV 44.4->41.7us).
//
// R6: T1 XCD-chunked block swizzle.  HW dispatch round-robins blocks over
// the 8 XCDs (private, non-coherent L2s); blocks sharing an operand panel
// land on different L2s and re-fetch from HBM.  Bijective remap (nwg%8==0
// for every per-z grid here) gives each XCD a contiguous band of work;
// MAJX picks which tile axis the band runs along so same-XCD blocks share
// the LARGER operand:
//   MAJX=1: band of bx (share A panel)  -- QK (A=x 16MB), PV (A=P 8MB/z)
//   MAJX=0: band of by (share B panel)  -- Vt (B=x 16MB)
// Pure index permutation: zero correctness risk.
//
// Swizzle (r5): staging slot s covers row r = s/CH, chunk
// (s%CH)^(r&(CH-1)) (CH = BK/8 16B-chunks per row); frag read XORs the same
// key: csw = ((t*4+quad)^(l15&(CH-1)))*8.  Conflict-free (measured 0).
//
// EPI: 1 = +bias[n], fp8 out (Q/K proj -> fp8 score inputs)
//      2 = +bias[m], bf16 out (Vt proj)
//      4 = acc * (1/sum16(gsum_row)) fp32 out (PV)
// ---------------------------------------------------------------------------
template <int BK, int EPI, int MAJX, typename OutT>
__global__ __launch_bounds__(256, (BK == 64) ? 4 : 2) void gemm_bt(
    const uint16_t* __restrict__ A, int lda, long long sAz,
    const uint16_t* __restrict__ B, int ldb, long long sBz,
    OutT* __restrict__ C, int ldc, long long sCz,
    const float* __restrict__ bias0, const float* __restrict__ bias1,
    float* __restrict__ gsum, int K, float alpha)
{
    constexpr int CH = BK / 8;     // 16B chunks per row (8 or 16)
    constexpr int NC = BK / 16;    // staging gloads per matrix per thread

    __shared__ uint16_t ldsA[128 * BK];
    __shared__ uint16_t ldsB[128 * BK];
    __shared__ float inv_denom[128];

    const int tid  = threadIdx.x;
    const int wave = tid >> 6;
    const int lane = tid & 63;
    const int quad = lane >> 4;
    const int l15  = lane & 15;
    const int z    = blockIdx.z;

    A += (long long)z * sAz;
    B += (long long)z * sBz;
    C += (long long)z * sCz;

    // ---- T1 XCD-chunked remap (per z-slice; nwg%8==0 at all call sites)
    int bx, by;
    {
        const int gx  = gridDim.x, gy = gridDim.y;
        const int nwg = gx * gy;
        int f = blockIdx.y * gx + blockIdx.x;      // hw dispatch order (x fastest)
        f = (f & 7) * (nwg >> 3) + (f >> 3);       // XCD k -> contiguous work band
        if (MAJX) { bx = f / gy; by = f % gy; }    // band runs along bx
        else      { by = f / gx; bx = f % gx; }    // band runs along by
    }
    const int m0 = bx * 128;
    const int n0 = by * 128;

    if (EPI == 4) {
        if (tid < 128) {
            const float* gp = gsum + (long long)z * 32768 + (m0 + tid) * 16;
            float s = 0.f;
#pragma unroll
            for (int t = 0; t < 16; ++t) s += gp[t];
            inv_denom[tid] = 1.f / s;
        }
        // visibility via the K-loop's first __syncthreads
    }

    const uint16_t* gA[NC];
    const uint16_t* gB[NC];
    uint16_t* lA[NC];
    uint16_t* lB[NC];
#pragma unroll
    for (int c = 0; c < NC; ++c) {
        const int s   = (c * 4 + wave) * 64 + lane;
        const int r   = s / CH;
        const int col = ((s & (CH - 1)) ^ (r & (CH - 1))) * 8;
        gA[c] = A + (long long)(m0 + r) * lda + col;
        gB[c] = B + (long long)(n0 + r) * ldb + col;
        lA[c] = ldsA + (c * 4 + wave) * 512;   // wave-uniform base
        lB[c] = ldsB + (c * 4 + wave) * 512;
    }

    const int m_off = (wave & 1) * 64;
    const int n_off = (wave >> 1) * 64;

    f32x4_t acc[4][4];
#pragma unroll
    for (int i = 0; i < 4; ++i)
#pragma unroll
        for (int j = 0; j < 4; ++j)
            acc[i][j] = f32x4_t{0.f, 0.f, 0.f, 0.f};

    for (int k0 = 0; k0 < K; k0 += BK) {
#pragma unroll
        for (int c = 0; c < NC; ++c) gload_lds16(gA[c], lA[c]);
#pragma unroll
        for (int c = 0; c < NC; ++c) gload_lds16(gB[c], lB[c]);
#pragma unroll
        for (int c = 0; c < NC; ++c) { gA[c] += BK; gB[c] += BK; }
        __syncthreads();

#pragma unroll
        for (int t = 0; t < BK / 32; ++t) {
            const int csw = ((t * 4 + quad) ^ (l15 & (CH - 1))) * 8;
            bf16x8_t af[4], bfr[4];
#pragma unroll
            for (int i = 0; i < 4; ++i)
                af[i] = *(const bf16x8_t*)(ldsA + (m_off + i * 16 + l15) * BK + csw);
#pragma unroll
            for (int j = 0; j < 4; ++j)
                bfr[j] = *(const bf16x8_t*)(ldsB + (n_off + j * 16 + l15) * BK + csw);
#pragma unroll
            for (int i = 0; i < 4; ++i)
#pragma unroll
                for (int j = 0; j < 4; ++j)
                    acc[i][j] = __builtin_amdgcn_mfma_f32_16x16x32_bf16(af[i], bfr[j], acc[i][j], 0, 0, 0);
        }
        __syncthreads();
    }

    if (EPI == 1 || EPI == 2) {
        const float* bias = (z == 0) ? bias0 : bias1;
#pragma unroll
        for (int i = 0; i < 4; ++i) {
            const int mb = m0 + m_off + i * 16 + quad * 4;
            float rb[4];
            if (EPI == 2) {
#pragma unroll
                for (int r = 0; r < 4; ++r) rb[r] = bias[mb + r];
            }
#pragma unroll
            for (int j = 0; j < 4; ++j) {
                const int n = n0 + n_off + j * 16 + l15;
                const float cb = (EPI == 1) ? bias[n] : 0.f;
#pragma unroll
                for (int r = 0; r < 4; ++r) {
                    const float v = acc[i][j][r] + ((EPI == 1) ? cb : rb[r]);
                    if (sizeof(OutT) == 1)
                        ((uint8_t*)C)[(long long)(mb + r) * ldc + n] = f2fp8(v);
                    else
                        ((uint16_t*)C)[(long long)(mb + r) * ldc + n] = f2bf(v);
                }
            }
        }
    } else {  // EPI == 4
#pragma unroll
        for (int i = 0; i < 4; ++i) {
            const int rl = m_off + i * 16 + quad * 4;
            const int mb = m0 + rl;
#pragma unroll
            for (int j = 0; j < 4; ++j) {
                const int n = n0 + n_off + j * 16 + l15;
#pragma unroll
                for (int r = 0; r < 4; ++r)
                    ((float*)C)[(long long)(mb + r) * ldc + n] =
                        acc[i][j][r] * inv_denom[rl + r];
            }
        }
    }
}

// ---------------------------------------------------------------------------
// fp8 score GEMM: P~ = exp((Q K^T)/32), MX-fp8 MFMA K=128 with unit scales.
// Tile 128x128, BK=128 fp8.  R6: + XCD-chunked swizzle (bx-major; Q/K both
// 2MB/z so either axis L2-fits — bx keeps the gsum slot = by mapping 1:1).
// ---------------------------------------------------------------------------
__global__ __launch_bounds__(256, 3) void score_f8(
    const uint8_t* __restrict__ Qf8, const uint8_t* __restrict__ Kf8,
    uint16_t* __restrict__ P, float* __restrict__ gsum, float alpha)
{
    __shared__ uint8_t ldsA[128 * 128];
    __shared__ uint8_t ldsB[128 * 128];

    const int tid  = threadIdx.x;
    const int wave = tid >> 6;
    const int lane = tid & 63;
    const int quad = lane >> 4;
    const int l15  = lane & 15;
    const int z    = blockIdx.z;

    const uint8_t* A = Qf8 + (long long)z * 2097152;
    const uint8_t* B = Kf8 + (long long)z * 2097152;
    uint16_t* C = P + (long long)z * 4194304;

    // ---- T1 XCD-chunked remap (nwg = 256 per z)
    int bx, by;
    {
        const int gx  = gridDim.x, gy = gridDim.y;
        const int nwg = gx * gy;
        int f = blockIdx.y * gx + blockIdx.x;
        f = (f & 7) * (nwg >> 3) + (f >> 3);
        bx = f / gy; by = f % gy;
    }
    const int m0 = bx * 128;
    const int n0 = by * 128;

    // staging: 1024 16B slots/side; slot s -> row r=s>>3, holds global chunk
    // (s&7)^(r&7) (16 fp8 k's per chunk, 8 chunks = 128 k per row).
    const uint8_t* gA[4];
    const uint8_t* gB[4];
    uint8_t* lA[4];
    uint8_t* lB[4];
#pragma unroll
    for (int c = 0; c < 4; ++c) {
        const int s   = (c * 4 + wave) * 64 + lane;
        const int r   = s >> 3;
        const int col = ((s & 7) ^ (r & 7)) * 16;
        gA[c] = A + (long long)(m0 + r) * 1024 + col;
        gB[c] = B + (long long)(n0 + r) * 1024 + col;
        lA[c] = ldsA + (c * 4 + wave) * 1024;   // wave-uniform base
        lB[c] = ldsB + (c * 4 + wave) * 1024;
    }

    const int m_off = (wave & 1) * 64;
    const int n_off = (wave >> 1) * 64;

    f32x4_t acc[4][4];
#pragma unroll
    for (int i = 0; i < 4; ++i)
#pragma unroll
        for (int j = 0; j < 4; ++j)
            acc[i][j] = f32x4_t{0.f, 0.f, 0.f, 0.f};

    // frag k = quad*32 + j (j 0..31): global chunks 2q (k 32q..+15) and
    // 2q+1 (k 32q+16..+31), swizzle-relocated independently.
    const int h0 = quad * 2;
    const int h1 = quad * 2 + 1;

    for (int k0 = 0; k0 < 1024; k0 += 128) {
#pragma unroll
        for (int c = 0; c < 4; ++c) gload_lds16(gA[c], lA[c]);
#pragma unroll
        for (int c = 0; c < 4; ++c) gload_lds16(gB[c], lB[c]);
#pragma unroll
        for (int c = 0; c < 4; ++c) { gA[c] += 128; gB[c] += 128; }
        __syncthreads();

        i32x8_t af[4], bfr[4];
#pragma unroll
        for (int i = 0; i < 4; ++i) {
            const int m = m_off + i * 16 + l15;
            const int sw = m & 7;
            const i32x4_t lo = *(const i32x4_t*)(ldsA + m * 128 + (h0 ^ sw) * 16);
            const i32x4_t hi = *(const i32x4_t*)(ldsA + m * 128 + (h1 ^ sw) * 16);
            af[i] = i32x8_t{lo[0], lo[1], lo[2], lo[3], hi[0], hi[1], hi[2], hi[3]};
        }
#pragma unroll
        for (int j = 0; j < 4; ++j) {
            const int n = n_off + j * 16 + l15;
            const int sw = n & 7;
            const i32x4_t lo = *(const i32x4_t*)(ldsB + n * 128 + (h0 ^ sw) * 16);
            const i32x4_t hi = *(const i32x4_t*)(ldsB + n * 128 + (h1 ^ sw) * 16);
            bfr[j] = i32x8_t{lo[0], lo[1], lo[2], lo[3], hi[0], hi[1], hi[2], hi[3]};
        }
#pragma unroll
        for (int i = 0; i < 4; ++i)
#pragma unroll
            for (int j = 0; j < 4; ++j)
                acc[i][j] = __builtin_amdgcn_mfma_scale_f32_16x16x128_f8f6f4(
                    af[i], bfr[j], acc[i][j],
                    0, 0,                       // cbsz, blgp: fp8 e4m3 / fp8 e4m3
                    0, 0x7f7f7f7f,              // opsel_a, scale_a (e8m0 127 = x1)
                    0, 0x7f7f7f7f);             // opsel_b, scale_b
        __syncthreads();
    }

    // EPI-3 epilogue (r5-verified, C/D layout shape-determined).
    float rs[4][4];
#pragma unroll
    for (int i = 0; i < 4; ++i)
#pragma unroll
        for (int r = 0; r < 4; ++r) rs[i][r] = 0.f;
#pragma unroll
    for (int i = 0; i < 4; ++i) {
        const int mb = m0 + m_off + i * 16 + quad * 4;
#pragma unroll
        for (int j = 0; j < 4; ++j) {
            const int n = n0 + n_off + j * 16 + l15;
#pragma unroll
            for (int r = 0; r < 4; ++r) {
                const float e = exp2f(acc[i][j][r] * alpha);
                rs[i][r] += e;
                C[(long long)(mb + r) * 2048 + n] = f2bf(e);
            }
        }
    }
#pragma unroll
    for (int m = 1; m < 16; m <<= 1)
#pragma unroll
        for (int i = 0; i < 4; ++i)
#pragma unroll
            for (int r = 0; r < 4; ++r)
                rs[i][r] += __shfl_xor(rs[i][r], m);
    float* lp = (float*)ldsA;   // reuse past last barrier: [4 waves][64 rows]
    if (l15 == 0) {
#pragma unroll
        for (int i = 0; i < 4; ++i)
#pragma unroll
            for (int r = 0; r < 4; ++r)
                lp[wave * 64 + i * 16 + quad * 4 + r] = rs[i][r];
    }
    __syncthreads();
    if (tid < 128) {
        const float s = lp[(tid >> 6) * 64 + (tid & 63)] +
                        lp[((tid >> 6) + 2) * 64 + (tid & 63)];
        gsum[(long long)z * 32768 + (m0 + tid) * 16 + by] = s;   // by = swizzled n-tile
    }
}

// fp32 -> bf16 for x (blocks 0..8191) and Wq/Wk/Wv (blocks 8192..11263).
__global__ void cvt_all(const float* __restrict__ x,
                        const float* __restrict__ Wq, const float* __restrict__ Wk,
                        const float* __restrict__ Wv,
                        uint16_t* __restrict__ x_bf, uint16_t* __restrict__ w_bf) {
    const int b = blockIdx.x;
    const float* src;
    uint16_t* dst;
    int i;
    if (b < 8192) {
        src = x; dst = x_bf; i = b * 256 + threadIdx.x;
    } else {
        const int wz = (b - 8192) >> 10;
        const int rb = (b - 8192) & 1023;
        src = (wz == 0) ? Wq : (wz == 1) ? Wk : Wv;
        dst = w_bf + (long long)wz * 1048576;
        i = rb * 256 + threadIdx.x;
    }
    const float4 f = ((const float4*)src)[i];
    ushort4 o;
    o.x = f2bf(f.x); o.y = f2bf(f.y); o.z = f2bf(f.z); o.w = f2bf(f.w);
    ((ushort4*)dst)[i] = o;
}

extern "C" void kernel_launch(void* const* d_in, const int* in_sizes, int n_in,
                              void* d_out, int out_size, void* d_ws, size_t ws_size,
                              hipStream_t stream) {
    const float* x  = (const float*)d_in[0];
    const float* Wq = (const float*)d_in[1];
    const float* bq = (const float*)d_in[2];
    const float* Wk = (const float*)d_in[3];
    const float* bk = (const float*)d_in[4];
    const float* Wv = (const float*)d_in[5];
    const float* bv = (const float*)d_in[6];
    float* out = (float*)d_out;

    char* w = (char*)d_ws;
    uint16_t* x_bf = (uint16_t*)(w);
    float*    gsum = (float*)(w);                 // overlays dead x_bf
    uint16_t* w_bf = (uint16_t*)(w + 16777216);
    uint8_t*  Qf8  = (uint8_t*)(w + 23068672);
    uint8_t*  Kf8  = (uint8_t*)(w + 31457280);
    uint16_t* Vt   = (uint16_t*)(w + 39845888);
    uint16_t* Pb   = (uint16_t*)(w + 56623104);

    // 1) fp32 -> bf16 conversions (x + all three W)
    cvt_all<<<11264, 256, 0, stream>>>(x, Wq, Wk, Wv, x_bf, w_bf);

    // 2) Q,K = x @ W^T + b   [8192,1024] fp8 out.  BK=64, 1024 wg (4/CU);
    //    MAJX=1: same-XCD blocks share the x A-panel (16 MB operand)
    gemm_bt<64, 1, 1, uint8_t><<<dim3(64, 8, 2), 256, 0, stream>>>(
        x_bf, 1024, 0LL,
        w_bf, 1024, 1048576LL,
        Qf8, 1024, 8388608LL,
        bq, bk, nullptr, 1024, 1.0f);

    // 2b) Vt[e, b*2048+s] = Wv x^T + bv  [1024,8192].  BK=128 (grid-limited);
    //     MAJX=0: same-XCD blocks share the x B-panel
    gemm_bt<128, 2, 0, uint16_t><<<dim3(8, 64, 1), 256, 0, stream>>>(
        w_bf + 2097152, 1024, 0LL,
        x_bf, 1024, 0LL,
        Vt, 8192, 0LL,
        bv, bv, nullptr, 1024, 1.0f);

    // 3) P~_b = exp((Q_b K_b^T)/32) via MX-fp8 K=128; alpha = (1/32)*log2(e)
    score_f8<<<dim3(16, 16, 4), 256, 0, stream>>>(
        Qf8, Kf8, Pb, gsum, 0.045084222f);

    // 4) O_b = (P~_b @ V_b) / denom : fp32 out.  BK=128 (grid-limited);
    //    MAJX=1: same-XCD blocks share the P A-panel (8 MB/z operand)
    gemm_bt<128, 4, 1, float><<<dim3(16, 8, 4), 256, 0, stream>>>(
        Pb, 2048, 4194304LL,
        Vt, 8192, 2048LL,
        out, 1024, 2097152LL,
        nullptr, nullptr, gsum, 2048, 1.0f);
}